// Round 6
// baseline (516.762 us; speedup 1.0000x reference)
//
#include <hip/hip_runtime.h>
#include <cstddef>
#include <cstdint>

// Problem constants (fixed by reference)
#define DMODEL 768
#define DINNER 1536
#define NSTATE 16
#define LSEQ   2048
#define NB     2
#define NTOK   (NB*LSEQ)        // 4096 tokens
#define NBCDT  33               // 1 + 2*16

// Chunked scan parameters
#define TC     64               // timesteps per chunk
#define NCHUNK (LSEQ/TC)        // 32
#define KSPLIT 6                // bcdt split-K factor (1536/256)

typedef __bf16 bf16x8 __attribute__((ext_vector_type(8)));
typedef float  floatx4 __attribute__((ext_vector_type(4)));
typedef unsigned short us8 __attribute__((ext_vector_type(8)));

__device__ __forceinline__ float silu_f(float x) { return x / (1.f + expf(-x)); }
__device__ __forceinline__ float clip1e4(float x) { return fminf(fmaxf(x, -1e4f), 1e4f); }
__device__ __forceinline__ unsigned short f2bf(float f) {   // RNE float->bf16 bits
    unsigned int u = __float_as_uint(f);
    unsigned int r = u + 0x7fffu + ((u >> 16) & 1u);
    return (unsigned short)(r >> 16);
}
__device__ __forceinline__ float bf2f(unsigned short u) {
    return __uint_as_float((unsigned int)u << 16);
}
// async global->LDS, 16B per lane; LDS dest = base + lane*16 (wave-uniform base)
__device__ __forceinline__ void ld_lds16(unsigned short* lds, const unsigned short* g) {
    __builtin_amdgcn_global_load_lds(
        (const __attribute__((address_space(1))) unsigned int*)g,
        (__attribute__((address_space(3))) unsigned int*)lds,
        16, 0, 0);
}

// ---------------------------------------------------------------------------
// Kernel 1: LayerNorm -> bf16 output. one block per token row.
// ---------------------------------------------------------------------------
__global__ void ln_kernel(const float* __restrict__ x,
                          const float* __restrict__ g,
                          const float* __restrict__ be,
                          unsigned short* __restrict__ xnb) {
    int row = blockIdx.x;
    int tid = threadIdx.x;
    const float* xr = x + (size_t)row * DMODEL;
    float s = 0.f, ss = 0.f;
    for (int i = tid; i < DMODEL; i += 256) {
        float v = xr[i];
        s += v; ss += v * v;
    }
    for (int o = 32; o >= 1; o >>= 1) {
        s  += __shfl_xor(s,  o, 64);
        ss += __shfl_xor(ss, o, 64);
    }
    __shared__ float sS[4], sSS[4];
    int w = tid >> 6;
    if ((tid & 63) == 0) { sS[w] = s; sSS[w] = ss; }
    __syncthreads();
    s  = sS[0] + sS[1] + sS[2] + sS[3];
    ss = sSS[0] + sSS[1] + sSS[2] + sSS[3];
    float mu = s / DMODEL;
    float var = ss / DMODEL - mu * mu;
    float rstd = rsqrtf(var + 1e-5f);
    unsigned short* xo = xnb + (size_t)row * DMODEL;
    for (int i = tid; i < DMODEL; i += 256)
        xo[i] = f2bf((xr[i] - mu) * rstd * g[i] + be[i]);
}

// ---------------------------------------------------------------------------
// Kernel 2a: transpose-cast in-proj weights: inwT[n][k] (bf16), n in [0,6144)
// ---------------------------------------------------------------------------
__global__ __launch_bounds__(256)
void cast_inwT(const float* __restrict__ fw, const float* __restrict__ bw,
               unsigned short* __restrict__ wT) {
    __shared__ float t[32][33];
    int n0 = blockIdx.x * 32;     // 192 blocks
    int k0 = blockIdx.y * 32;     // 24 blocks
    int tid = threadIdx.x;
    int lr = tid >> 5, lc = tid & 31;
    const float* w = (n0 >= 3072) ? bw : fw;
    int nb = (n0 >= 3072) ? (n0 - 3072) : n0;
    #pragma unroll
    for (int r = 0; r < 4; r++)
        t[r * 8 + lr][lc] = w[(size_t)(k0 + r * 8 + lr) * 3072 + nb + lc];
    __syncthreads();
    #pragma unroll
    for (int r = 0; r < 4; r++)
        wT[(size_t)(n0 + r * 8 + lr) * DMODEL + k0 + lc] = f2bf(t[lc][r * 8 + lr]);
}

// ---------------------------------------------------------------------------
// Kernel 2b: transpose-cast out-proj weights with blend scale folded in.
// ---------------------------------------------------------------------------
__global__ __launch_bounds__(256)
void cast_outwT(const float* __restrict__ fw, const float* __restrict__ bw,
                const float* __restrict__ alpha, unsigned short* __restrict__ wT) {
    __shared__ float t[32][33];
    float a = 1.f / (1.f + expf(-alpha[0]));
    int n0 = blockIdx.x * 32;     // 24 blocks
    int k0 = blockIdx.y * 32;     // 96 blocks
    int tid = threadIdx.x;
    int lr = tid >> 5, lc = tid & 31;
    const float* w = (k0 >= DINNER) ? bw : fw;
    float sc = (k0 >= DINNER) ? (1.f - a) : a;
    int kb = (k0 >= DINNER) ? (k0 - DINNER) : k0;
    #pragma unroll
    for (int r = 0; r < 4; r++)
        t[r * 8 + lr][lc] = w[(size_t)(kb + r * 8 + lr) * DMODEL + n0 + lc];
    __syncthreads();
    #pragma unroll
    for (int r = 0; r < 4; r++)
        wT[(size_t)(n0 + r * 8 + lr) * 3072 + k0 + lc] = f2bf(sc * t[lc][r * 8 + lr]);
}

// ---------------------------------------------------------------------------
// Kernel 3: xz GEMM via MFMA bf16, m97-style async LDS staging.
// M=4096, N=6144, K=768.  128x128 tile, BK=64, unpadded LDS (stride 64).
// Epilogue: bf16 xi / silu->bf16 sz.
// ---------------------------------------------------------------------------
__global__ __launch_bounds__(256)
void gemm_xz_mfma(const unsigned short* __restrict__ xnb,
                  const unsigned short* __restrict__ inwT,
                  unsigned short* __restrict__ xi, unsigned short* __restrict__ sz) {
    __shared__ unsigned short Asm[128 * 64];
    __shared__ unsigned short Bsm[128 * 64];
    int tid = threadIdx.x;
    int bm = blockIdx.y * 128;
    int bn = blockIdx.x * 128;
    int wave = tid >> 6, lane = tid & 63;
    int wm = (wave & 1) * 64, wn = (wave >> 1) * 64;
    int col15 = lane & 15, quad = lane >> 4;
    int lrow = lane >> 3;           // 0..7  (row within 8-row chunk)
    int lk   = (lane & 7) * 8;      // bf16 col offset (16B per lane)
    floatx4 acc[4][4];
    #pragma unroll
    for (int i = 0; i < 4; i++)
        #pragma unroll
        for (int j = 0; j < 4; j++)
            acc[i][j] = (floatx4){0.f, 0.f, 0.f, 0.f};

    for (int k0 = 0; k0 < DMODEL; k0 += 64) {
        // async staging: each wave fills rows [wave*32, wave*32+32) of A and B
        #pragma unroll
        for (int i = 0; i < 4; i++) {
            int r8 = wave * 32 + i * 8;          // chunk base row
            int ra = r8 + lrow;
            ld_lds16(&Asm[r8 * 64], &xnb[(size_t)(bm + ra) * DMODEL + k0 + lk]);
            ld_lds16(&Bsm[r8 * 64], &inwT[(size_t)(bn + ra) * DMODEL + k0 + lk]);
        }
        __syncthreads();   // drains vmcnt -> staged data visible
        #pragma unroll
        for (int k2 = 0; k2 < 2; k2++) {
            bf16x8 af[4], bf_[4];
            #pragma unroll
            for (int mt = 0; mt < 4; mt++)
                af[mt] = *(const bf16x8*)(&Asm[(wm + mt * 16 + col15) * 64 + k2 * 32 + quad * 8]);
            #pragma unroll
            for (int nt = 0; nt < 4; nt++)
                bf_[nt] = *(const bf16x8*)(&Bsm[(wn + nt * 16 + col15) * 64 + k2 * 32 + quad * 8]);
            #pragma unroll
            for (int mt = 0; mt < 4; mt++)
                #pragma unroll
                for (int nt = 0; nt < 4; nt++)
                    acc[mt][nt] = __builtin_amdgcn_mfma_f32_16x16x32_bf16(
                        af[mt], bf_[nt], acc[mt][nt], 0, 0, 0);
        }
        __syncthreads();
    }
    #pragma unroll
    for (int mt = 0; mt < 4; mt++) {
        #pragma unroll
        for (int nt = 0; nt < 4; nt++) {
            #pragma unroll
            for (int r = 0; r < 4; r++) {
                int row = bm + wm + mt * 16 + quad * 4 + r;
                int gn  = bn + wn + nt * 16 + col15;
                float v = acc[mt][nt][r];
                int dir = (gn >= 3072) ? 1 : 0;
                int cc = gn - dir * 3072;
                size_t base = ((size_t)dir * NTOK + row) * DINNER;
                if (cc < DINNER) xi[base + cc] = f2bf(v);
                else             sz[base + cc - DINNER] = f2bf(silu_f(v));
            }
        }
    }
}

// ---------------------------------------------------------------------------
// Kernel 4: depthwise causal conv (k=4) + bias + SiLU.
// bf16 input (ushort8 = 8 channels/thread), fp32 output.
// ---------------------------------------------------------------------------
__global__ void conv_silu(const unsigned short* __restrict__ xi,
                          const float* __restrict__ f_cw, const float* __restrict__ f_cb,
                          const float* __restrict__ b_cw, const float* __restrict__ b_cb,
                          float* __restrict__ xc) {
    const int D8 = DINNER / 8;        // 192
    size_t gid = (size_t)blockIdx.x * 256 + threadIdx.x;
    const size_t total = (size_t)2 * NTOK * D8;
    if (gid >= total) return;
    int d8 = (int)(gid % D8);
    size_t r = gid / D8;              // (dir*2+b)*LSEQ + t
    int t = (int)(r % LSEQ);
    int b = (int)((r / LSEQ) % NB);
    int dir = (int)(r / (LSEQ * NB));
    int d = d8 * 8;
    const float* cw = dir ? b_cw : f_cw;
    const float* cb = dir ? b_cb : f_cb;
    float acc[8], w[4][8];
    #pragma unroll
    for (int j = 0; j < 8; j++) {
        acc[j] = cb[d + j];
        float4 wj = *(const float4*)(cw + (size_t)(d + j) * 4);
        w[0][j] = wj.x; w[1][j] = wj.y; w[2][j] = wj.z; w[3][j] = wj.w;
    }
    size_t xib = ((size_t)dir * NTOK + (size_t)b * LSEQ) * DINNER + d;
    #pragma unroll
    for (int k = 0; k < 4; k++) {
        int u = t - 3 + k;
        if (u < 0) continue;
        int l = dir ? (LSEQ - 1 - u) : u;
        us8 xv = *(const us8*)(xi + xib + (size_t)l * DINNER);
        #pragma unroll
        for (int j = 0; j < 8; j++)
            acc[j] = fmaf(w[k][j], bf2f(xv[j]), acc[j]);
    }
    float* xo = xc + r * DINNER + d;
    float4 o0, o1;
    o0.x = silu_f(acc[0]); o0.y = silu_f(acc[1]); o0.z = silu_f(acc[2]); o0.w = silu_f(acc[3]);
    o1.x = silu_f(acc[4]); o1.y = silu_f(acc[5]); o1.z = silu_f(acc[6]); o1.w = silu_f(acc[7]);
    *(float4*)xo = o0;
    *(float4*)(xo + 4) = o1;
}

// ---------------------------------------------------------------------------
// Kernel 5a: bcdt split-K partials. grid (128 row-blocks, KSPLIT).
// ---------------------------------------------------------------------------
__global__ __launch_bounds__(256)
void bcdt_gemm(const float* __restrict__ xc,
               const float* __restrict__ f_xw,
               const float* __restrict__ b_xw,
               float* __restrict__ part) {
    __shared__ float As[64][33];
    __shared__ float Ws[32 * 33];
    int r0 = blockIdx.x * 64;
    int kc = blockIdx.y;
    const float* xw = (r0 >= NTOK) ? b_xw : f_xw;
    int tid = threadIdx.x;
    int m = tid >> 2, jq = tid & 3;
    float acc[9] = {};
    int kend = kc * 256 + 256;
    for (int k0 = kc * 256; k0 < kend; k0 += 32) {
        for (int i = tid; i < 64 * 32; i += 256) {
            int mm = i >> 5, k = i & 31;
            As[mm][k] = xc[((size_t)r0 + mm) * DINNER + k0 + k];
        }
        for (int i = tid; i < 32 * 33; i += 256)
            Ws[i] = xw[(size_t)k0 * 33 + i];
        __syncthreads();
        #pragma unroll 8
        for (int k = 0; k < 32; k++) {
            float a = As[m][k];
            #pragma unroll
            for (int jj = 0; jj < 9; jj++) {
                int j = jq + jj * 4;
                if (j < 33) acc[jj] = fmaf(a, Ws[k * 33 + j], acc[jj]);
            }
        }
        __syncthreads();
    }
    #pragma unroll
    for (int jj = 0; jj < 9; jj++) {
        int j = jq + jj * 4;
        if (j < 33)
            part[((size_t)kc * (2 * NTOK) + r0 + m) * 33 + j] = acc[jj];
    }
}

// ---------------------------------------------------------------------------
// Kernel 5b: reduce split-K partials.
// ---------------------------------------------------------------------------
__global__ void bcdt_reduce(const float* __restrict__ part, float* __restrict__ bcdt) {
    int i = blockIdx.x * 256 + threadIdx.x;
    const int total = 2 * NTOK * NBCDT;       // 270,336
    if (i >= total) return;
    float s = 0.f;
    #pragma unroll
    for (int kc = 0; kc < KSPLIT; kc++)
        s += part[(size_t)kc * total + i];
    bcdt[i] = s;
}

// ---------------------------------------------------------------------------
// Kernel 6a: chunked scan phase 1 -- one THREAD per channel, h[16] in regs.
// ---------------------------------------------------------------------------
__global__ __launch_bounds__(256)
void scan_p1(const float* __restrict__ xc, const float* __restrict__ bcdt,
             const float* __restrict__ f_dtw, const float* __restrict__ f_dtb,
             const float* __restrict__ f_Alog,
             const float* __restrict__ b_dtw, const float* __restrict__ b_dtb,
             const float* __restrict__ b_Alog,
             float* __restrict__ Pbuf, float* __restrict__ hloc) {
    int tid = threadIdx.x;
    int d = blockIdx.x * 256 + tid;
    int chunk = blockIdx.y;
    int dirb  = blockIdx.z;
    int dir = dirb >> 1;
    const float* dtw  = dir ? b_dtw  : f_dtw;
    const float* dtb  = dir ? b_dtb  : f_dtb;
    const float* Alog = dir ? b_Alog : f_Alog;
    float dtw_d = dtw[d], dtb_d = dtb[d];
    float A[NSTATE], h[NSTATE];
    #pragma unroll
    for (int s = 0; s < NSTATE; s++) {
        float al = fminf(fmaxf(Alog[d * NSTATE + s], -6.f), 6.f);
        A[s] = -__expf(al);
        h[s] = 0.f;
    }
    float Sdt = 0.f;
    size_t rbase = (size_t)dirb * LSEQ + (size_t)chunk * TC;
    const float* bc = bcdt + rbase * NBCDT;
    const float* xp = xc + rbase * DINNER + d;
    for (int t = 0; t < TC; t++) {
        float xv = xp[(size_t)t * DINNER];
        float dt_raw = bc[t * NBCDT];
        float u = fmaf(dt_raw, dtw_d, dtb_d);
        float dt = fmaxf(u, 0.f) + __logf(1.f + __expf(-fabsf(u)));
        Sdt += dt;
        float dtx = dt * xv;
        #pragma unroll
        for (int s = 0; s < NSTATE; s++) {
            float Bv = bc[t * NBCDT + 1 + s];
            h[s] = clip1e4(fmaf(__expf(dt * A[s]), h[s], dtx * Bv));
        }
    }
    size_t base = ((size_t)chunk * 4 + dirb) * ((size_t)DINNER * NSTATE) + (size_t)d * NSTATE;
    #pragma unroll
    for (int s = 0; s < NSTATE; s++) {
        Pbuf[base + s] = __expf(A[s] * Sdt);
        hloc[base + s] = h[s];
    }
}

// ---------------------------------------------------------------------------
// Kernel 6b: phase 2 -- stitch chunk boundary states.
// ---------------------------------------------------------------------------
__global__ void scan_p2(const float* __restrict__ Pbuf, const float* __restrict__ hloc,
                        float* __restrict__ hin) {
    int i = blockIdx.x * 256 + threadIdx.x;
    float h = 0.f;
    const int stride = 4 * DINNER * NSTATE;   // 98304
    for (int c = 0; c < NCHUNK; c++) {
        size_t idx = (size_t)c * stride + i;
        hin[idx] = h;
        h = clip1e4(fmaf(Pbuf[idx], h, hloc[idx]));
    }
}

// ---------------------------------------------------------------------------
// Kernel 6c: phase 3 -- re-run from stitched h_in, thread-per-channel,
// write bf16 yvb [4096][3072].  sz is bf16.
// ---------------------------------------------------------------------------
__global__ __launch_bounds__(256)
void scan_p3(const float* __restrict__ xc, const float* __restrict__ bcdt,
             const unsigned short* __restrict__ sz, const float* __restrict__ hin,
             const float* __restrict__ f_dtw, const float* __restrict__ f_dtb,
             const float* __restrict__ f_Alog, const float* __restrict__ f_D,
             const float* __restrict__ b_dtw, const float* __restrict__ b_dtb,
             const float* __restrict__ b_Alog, const float* __restrict__ b_D,
             unsigned short* __restrict__ yvb) {
    int tid = threadIdx.x;
    int d = blockIdx.x * 256 + tid;
    int chunk = blockIdx.y;
    int dirb  = blockIdx.z;
    int dir = dirb >> 1, b = dirb & 1;
    const float* dtw  = dir ? b_dtw  : f_dtw;
    const float* dtb  = dir ? b_dtb  : f_dtb;
    const float* Alog = dir ? b_Alog : f_Alog;
    const float* Dp   = dir ? b_D    : f_D;
    float dtw_d = dtw[d], dtb_d = dtb[d], D_d = Dp[d];
    float A[NSTATE], h[NSTATE];
    size_t hbase = ((size_t)chunk * 4 + dirb) * ((size_t)DINNER * NSTATE) + (size_t)d * NSTATE;
    #pragma unroll
    for (int s = 0; s < NSTATE; s++) {
        float al = fminf(fmaxf(Alog[d * NSTATE + s], -6.f), 6.f);
        A[s] = -__expf(al);
        h[s] = hin[hbase + s];
    }
    size_t rbase = (size_t)dirb * LSEQ + (size_t)chunk * TC;
    const float* bc = bcdt + rbase * NBCDT;
    const float* xp = xc + rbase * DINNER + d;
    int t0 = chunk * TC;
    for (int t = 0; t < TC; t++) {
        float xv = xp[(size_t)t * DINNER];
        float dt_raw = bc[t * NBCDT];
        float u = fmaf(dt_raw, dtw_d, dtb_d);
        float dt = fmaxf(u, 0.f) + __logf(1.f + __expf(-fabsf(u)));
        float dtx = dt * xv;
        float p = 0.f;
        #pragma unroll
        for (int s = 0; s < NSTATE; s++) {
            float Bv = bc[t * NBCDT + 1 + s];
            float Cv = bc[t * NBCDT + 1 + NSTATE + s];
            h[s] = clip1e4(fmaf(__expf(dt * A[s]), h[s], dtx * Bv));
            p = fmaf(h[s], Cv, p);
        }
        int tt = t0 + t;
        int l = dir ? (LSEQ - 1 - tt) : tt;
        float szv = bf2f(sz[((size_t)dir * NTOK + (size_t)b * LSEQ + l) * DINNER + d]);
        float y = (p + xv * D_d) * szv;
        int row = b * LSEQ + l;
        yvb[(size_t)row * 3072 + dir * DINNER + d] = f2bf(y);
    }
}

// ---------------------------------------------------------------------------
// Kernel 7: output GEMM via MFMA bf16 + residual, async LDS staging.
// M=4096, N=768, K=3072.  128x64 tile, BK=64, unpadded LDS.
// ---------------------------------------------------------------------------
__global__ __launch_bounds__(256)
void gemm_out_mfma(const unsigned short* __restrict__ yvb,
                   const unsigned short* __restrict__ outwT,
                   const float* __restrict__ x,
                   float* __restrict__ out) {
    __shared__ unsigned short Asm[128 * 64];
    __shared__ unsigned short Bsm[64 * 64];
    int tid = threadIdx.x;
    int bm = blockIdx.y * 128;
    int bn = blockIdx.x * 64;
    int wave = tid >> 6, lane = tid & 63;
    int wm = (wave & 1) * 64, wn = (wave >> 1) * 32;
    int col15 = lane & 15, quad = lane >> 4;
    int lrow = lane >> 3;
    int lk   = (lane & 7) * 8;
    floatx4 acc[4][2];
    #pragma unroll
    for (int i = 0; i < 4; i++)
        #pragma unroll
        for (int j = 0; j < 2; j++)
            acc[i][j] = (floatx4){0.f, 0.f, 0.f, 0.f};

    for (int k0 = 0; k0 < 2 * DINNER; k0 += 64) {
        #pragma unroll
        for (int i = 0; i < 4; i++) {
            int r8 = wave * 32 + i * 8;
            ld_lds16(&Asm[r8 * 64], &yvb[(size_t)(bm + r8 + lrow) * 3072 + k0 + lk]);
        }
        #pragma unroll
        for (int i = 0; i < 2; i++) {
            int r8 = wave * 16 + i * 8;
            ld_lds16(&Bsm[r8 * 64], &outwT[(size_t)(bn + r8 + lrow) * 3072 + k0 + lk]);
        }
        __syncthreads();
        #pragma unroll
        for (int k2 = 0; k2 < 2; k2++) {
            bf16x8 af[4], bf_[2];
            #pragma unroll
            for (int mt = 0; mt < 4; mt++)
                af[mt] = *(const bf16x8*)(&Asm[(wm + mt * 16 + col15) * 64 + k2 * 32 + quad * 8]);
            #pragma unroll
            for (int nt = 0; nt < 2; nt++)
                bf_[nt] = *(const bf16x8*)(&Bsm[(wn + nt * 16 + col15) * 64 + k2 * 32 + quad * 8]);
            #pragma unroll
            for (int mt = 0; mt < 4; mt++)
                #pragma unroll
                for (int nt = 0; nt < 2; nt++)
                    acc[mt][nt] = __builtin_amdgcn_mfma_f32_16x16x32_bf16(
                        af[mt], bf_[nt], acc[mt][nt], 0, 0, 0);
        }
        __syncthreads();
    }
    #pragma unroll
    for (int mt = 0; mt < 4; mt++) {
        #pragma unroll
        for (int nt = 0; nt < 2; nt++) {
            #pragma unroll
            for (int r = 0; r < 4; r++) {
                int row = bm + wm + mt * 16 + quad * 4 + r;
                int gn  = bn + wn + nt * 16 + col15;
                out[(size_t)row * DMODEL + gn] = acc[mt][nt][r] + x[(size_t)row * DMODEL + gn];
            }
        }
    }
}

// ---------------------------------------------------------------------------
extern "C" void kernel_launch(void* const* d_in, const int* in_sizes, int n_in,
                              void* d_out, int out_size, void* d_ws, size_t ws_size,
                              hipStream_t stream) {
    const float* x     = (const float*)d_in[0];
    const float* ln_g  = (const float*)d_in[1];
    const float* ln_b  = (const float*)d_in[2];
    const float* alpha = (const float*)d_in[3];
    const float* f_inw  = (const float*)d_in[4];
    const float* f_cw   = (const float*)d_in[5];
    const float* f_cb   = (const float*)d_in[6];
    const float* f_xw   = (const float*)d_in[7];
    const float* f_dtw  = (const float*)d_in[8];
    const float* f_dtb  = (const float*)d_in[9];
    const float* f_Alog = (const float*)d_in[10];
    const float* f_D    = (const float*)d_in[11];
    const float* f_outw = (const float*)d_in[12];
    const float* b_inw  = (const float*)d_in[13];
    const float* b_cw   = (const float*)d_in[14];
    const float* b_cb   = (const float*)d_in[15];
    const float* b_xw   = (const float*)d_in[16];
    const float* b_dtw  = (const float*)d_in[17];
    const float* b_dtb  = (const float*)d_in[18];
    const float* b_Alog = (const float*)d_in[19];
    const float* b_D    = (const float*)d_in[20];
    const float* b_outw = (const float*)d_in[21];
    float* out = (float*)d_out;

    // Workspace layout (float offsets; total 36.8M floats = 147 MB,
    // below the 172 MB footprint already validated in rounds 4-5):
    float* ws = (float*)d_ws;
    const size_t big = (size_t)2 * NTOK * DINNER;             // 12,582,912
    const size_t SUM = (size_t)NCHUNK * 4 * DINNER * NSTATE;  // 3,145,728 (TC=64)
    float* r_xnb  = ws;                        // 1,572,864 (xnb bf16); dead after gemm_xz
    float* r_inwT = r_xnb + 1572864;           // 2,359,296 (inwT bf16); dead after gemm_xz
    float* r_outwT= r_inwT + 2359296;          // 1,179,648 (outwT bf16); live till gemm_out
    float* r_xib  = r_outwT + 1179648;         // 6,291,456 (xi bf16); dead after conv -> yvb
    float* r_szb  = r_xib + 6291456;           // 6,291,456 (sz bf16)
    float* xc     = r_szb + 6291456;           // 12,582,912 (fp32)
    float* bcdt   = xc + big;                  // 270,336
    float* hin    = bcdt + 270336;             // 3,145,728
    float* hloc   = hin + 3145728;             // 3,145,728

    unsigned short* xnb   = (unsigned short*)r_xnb;
    unsigned short* inwT  = (unsigned short*)r_inwT;
    unsigned short* outwT = (unsigned short*)r_outwT;
    unsigned short* xib   = (unsigned short*)r_xib;
    unsigned short* szb   = (unsigned short*)r_szb;
    unsigned short* yvb   = (unsigned short*)r_xib;  // alias: xi dead after conv
    // bcdt_part (1,622,016 fl) aliases r_xnb + start of r_inwT (both dead after gemm_xz;
    // dead again before scan_p1 writes Pbuf into the same region)
    float* bcdt_part = r_xnb;
    float* Pbuf = r_xnb;                             // SUM fl, spans r_xnb + part of r_inwT

    // 1. LayerNorm -> bf16
    ln_kernel<<<NTOK, 256, 0, stream>>>(x, ln_g, ln_b, xnb);
    // 2. weight transpose-casts
    {
        dim3 g1(6144 / 32, DMODEL / 32);
        cast_inwT<<<g1, 256, 0, stream>>>(f_inw, b_inw, inwT);
        dim3 g2(DMODEL / 32, 3072 / 32);
        cast_outwT<<<g2, 256, 0, stream>>>(f_outw, b_outw, alpha, outwT);
    }
    // 3. xz GEMM (MFMA, async staging, bf16 out)
    {
        dim3 grid(6144 / 128, NTOK / 128);
        gemm_xz_mfma<<<grid, 256, 0, stream>>>(xnb, inwT, xib, szb);
    }
    // 4. conv + silu (bf16 in, fp32 out)
    {
        size_t total = (size_t)2 * NTOK * (DINNER / 8);
        conv_silu<<<(total + 255) / 256, 256, 0, stream>>>(xib, f_cw, f_cb, b_cw, b_cb, xc);
    }
    // 5. bcdt split-K GEMM + reduce
    {
        dim3 g(2 * NTOK / 64, KSPLIT);
        bcdt_gemm<<<g, 256, 0, stream>>>(xc, f_xw, b_xw, bcdt_part);
        bcdt_reduce<<<(2 * NTOK * NBCDT + 255) / 256, 256, 0, stream>>>(bcdt_part, bcdt);
    }
    // 6. chunked scan (thread-per-channel, TC=64)
    {
        dim3 grid1(DINNER / 256, NCHUNK, 4);
        scan_p1<<<grid1, 256, 0, stream>>>(xc, bcdt,
                                           f_dtw, f_dtb, f_Alog,
                                           b_dtw, b_dtb, b_Alog, Pbuf, hloc);
        scan_p2<<<(4 * DINNER * NSTATE) / 256, 256, 0, stream>>>(Pbuf, hloc, hin);
        scan_p3<<<grid1, 256, 0, stream>>>(xc, bcdt, szb, hin,
                                           f_dtw, f_dtb, f_Alog, f_D,
                                           b_dtw, b_dtb, b_Alog, b_D, yvb);
    }
    // 7. out GEMM (MFMA, async staging) + residual
    {
        dim3 grid(DMODEL / 64, NTOK / 128);
        gemm_out_mfma<<<grid, 256, 0, stream>>>(yvb, outwT, x, out);
    }
}

// Round 7
// 493.514 us; speedup vs baseline: 1.0471x; 1.0471x over previous
//
#include <hip/hip_runtime.h>
#include <cstddef>
#include <cstdint>

// Problem constants (fixed by reference)
#define DMODEL 768
#define DINNER 1536
#define NSTATE 16
#define LSEQ   2048
#define NB     2
#define NTOK   (NB*LSEQ)        // 4096 tokens
#define NBCDT  33               // 1 + 2*16

// Chunked scan parameters
#define TC     64               // timesteps per chunk
#define NCHUNK (LSEQ/TC)        // 32
#define KSPLIT 6                // bcdt split-K factor (1536/256)

typedef __bf16 bf16x8 __attribute__((ext_vector_type(8)));
typedef float  floatx4 __attribute__((ext_vector_type(4)));
typedef unsigned short us8 __attribute__((ext_vector_type(8)));

__device__ __forceinline__ float silu_f(float x) { return x / (1.f + expf(-x)); }
__device__ __forceinline__ float clip1e4(float x) { return fminf(fmaxf(x, -1e4f), 1e4f); }
__device__ __forceinline__ unsigned short f2bf(float f) {   // RNE float->bf16 bits
    unsigned int u = __float_as_uint(f);
    unsigned int r = u + 0x7fffu + ((u >> 16) & 1u);
    return (unsigned short)(r >> 16);
}
__device__ __forceinline__ float bf2f(unsigned short u) {
    return __uint_as_float((unsigned int)u << 16);
}
// async global->LDS, 16B per lane; LDS dest = base + lane*16 (wave-uniform base)
__device__ __forceinline__ void ld_lds16(unsigned short* lds, const unsigned short* g) {
    __builtin_amdgcn_global_load_lds(
        (const __attribute__((address_space(1))) unsigned int*)g,
        (__attribute__((address_space(3))) unsigned int*)lds,
        16, 0, 0);
}

// ---------------------------------------------------------------------------
// Kernel 1: LayerNorm -> bf16 output. one block per token row.
// ---------------------------------------------------------------------------
__global__ void ln_kernel(const float* __restrict__ x,
                          const float* __restrict__ g,
                          const float* __restrict__ be,
                          unsigned short* __restrict__ xnb) {
    int row = blockIdx.x;
    int tid = threadIdx.x;
    const float* xr = x + (size_t)row * DMODEL;
    float s = 0.f, ss = 0.f;
    for (int i = tid; i < DMODEL; i += 256) {
        float v = xr[i];
        s += v; ss += v * v;
    }
    for (int o = 32; o >= 1; o >>= 1) {
        s  += __shfl_xor(s,  o, 64);
        ss += __shfl_xor(ss, o, 64);
    }
    __shared__ float sS[4], sSS[4];
    int w = tid >> 6;
    if ((tid & 63) == 0) { sS[w] = s; sSS[w] = ss; }
    __syncthreads();
    s  = sS[0] + sS[1] + sS[2] + sS[3];
    ss = sSS[0] + sSS[1] + sSS[2] + sSS[3];
    float mu = s / DMODEL;
    float var = ss / DMODEL - mu * mu;
    float rstd = rsqrtf(var + 1e-5f);
    unsigned short* xo = xnb + (size_t)row * DMODEL;
    for (int i = tid; i < DMODEL; i += 256)
        xo[i] = f2bf((xr[i] - mu) * rstd * g[i] + be[i]);
}

// ---------------------------------------------------------------------------
// Kernel 2a: transpose-cast in-proj weights: inwT[n][k] (bf16), n in [0,6144)
// ---------------------------------------------------------------------------
__global__ __launch_bounds__(256)
void cast_inwT(const float* __restrict__ fw, const float* __restrict__ bw,
               unsigned short* __restrict__ wT) {
    __shared__ float t[32][33];
    int n0 = blockIdx.x * 32;     // 192 blocks
    int k0 = blockIdx.y * 32;     // 24 blocks
    int tid = threadIdx.x;
    int lr = tid >> 5, lc = tid & 31;
    const float* w = (n0 >= 3072) ? bw : fw;
    int nb = (n0 >= 3072) ? (n0 - 3072) : n0;
    #pragma unroll
    for (int r = 0; r < 4; r++)
        t[r * 8 + lr][lc] = w[(size_t)(k0 + r * 8 + lr) * 3072 + nb + lc];
    __syncthreads();
    #pragma unroll
    for (int r = 0; r < 4; r++)
        wT[(size_t)(n0 + r * 8 + lr) * DMODEL + k0 + lc] = f2bf(t[lc][r * 8 + lr]);
}

// ---------------------------------------------------------------------------
// Kernel 2b: transpose-cast out-proj weights with blend scale folded in.
// ---------------------------------------------------------------------------
__global__ __launch_bounds__(256)
void cast_outwT(const float* __restrict__ fw, const float* __restrict__ bw,
                const float* __restrict__ alpha, unsigned short* __restrict__ wT) {
    __shared__ float t[32][33];
    float a = 1.f / (1.f + expf(-alpha[0]));
    int n0 = blockIdx.x * 32;     // 24 blocks
    int k0 = blockIdx.y * 32;     // 96 blocks
    int tid = threadIdx.x;
    int lr = tid >> 5, lc = tid & 31;
    const float* w = (k0 >= DINNER) ? bw : fw;
    float sc = (k0 >= DINNER) ? (1.f - a) : a;
    int kb = (k0 >= DINNER) ? (k0 - DINNER) : k0;
    #pragma unroll
    for (int r = 0; r < 4; r++)
        t[r * 8 + lr][lc] = w[(size_t)(kb + r * 8 + lr) * DMODEL + n0 + lc];
    __syncthreads();
    #pragma unroll
    for (int r = 0; r < 4; r++)
        wT[(size_t)(n0 + r * 8 + lr) * 3072 + k0 + lc] = f2bf(sc * t[lc][r * 8 + lr]);
}

// ---------------------------------------------------------------------------
// Kernel 3: xz GEMM via MFMA bf16, async LDS staging + XOR-swizzled layout.
// M=4096, N=6144, K=768.  128x128 tile, BK=64, stride 64 (no pad).
// LDS row r, logical 8-elem chunk c stored at physical chunk c^(r&7):
//   staging lane (lrow, c) fetches global chunk c^lrow -> conflict-free
//   ds_read_b128 across col15 covers all 32 banks (2 lanes/bank = free).
// ---------------------------------------------------------------------------
__global__ __launch_bounds__(256)
void gemm_xz_mfma(const unsigned short* __restrict__ xnb,
                  const unsigned short* __restrict__ inwT,
                  unsigned short* __restrict__ xi, unsigned short* __restrict__ sz) {
    __shared__ unsigned short Asm[128 * 64];
    __shared__ unsigned short Bsm[128 * 64];
    int tid = threadIdx.x;
    int bm = blockIdx.y * 128;
    int bn = blockIdx.x * 128;
    int wave = tid >> 6, lane = tid & 63;
    int wm = (wave & 1) * 64, wn = (wave >> 1) * 64;
    int col15 = lane & 15, quad = lane >> 4;
    int lrow = lane >> 3;                      // 0..7
    int lk   = (((lane & 7) ^ lrow) * 8);      // swizzled global chunk offset
    floatx4 acc[4][4];
    #pragma unroll
    for (int i = 0; i < 4; i++)
        #pragma unroll
        for (int j = 0; j < 4; j++)
            acc[i][j] = (floatx4){0.f, 0.f, 0.f, 0.f};

    int sw = col15 & 7;                        // fragment-read swizzle key
    for (int k0 = 0; k0 < DMODEL; k0 += 64) {
        #pragma unroll
        for (int i = 0; i < 4; i++) {
            int r8 = wave * 32 + i * 8;
            int ra = r8 + lrow;
            ld_lds16(&Asm[r8 * 64], &xnb[(size_t)(bm + ra) * DMODEL + k0 + lk]);
            ld_lds16(&Bsm[r8 * 64], &inwT[(size_t)(bn + ra) * DMODEL + k0 + lk]);
        }
        __syncthreads();
        #pragma unroll
        for (int k2 = 0; k2 < 2; k2++) {
            bf16x8 af[4], bf_[4];
            int pc = ((k2 * 4 + quad) ^ sw) * 8;   // physical chunk offset
            #pragma unroll
            for (int mt = 0; mt < 4; mt++)
                af[mt] = *(const bf16x8*)(&Asm[(wm + mt * 16 + col15) * 64 + pc]);
            #pragma unroll
            for (int nt = 0; nt < 4; nt++)
                bf_[nt] = *(const bf16x8*)(&Bsm[(wn + nt * 16 + col15) * 64 + pc]);
            #pragma unroll
            for (int mt = 0; mt < 4; mt++)
                #pragma unroll
                for (int nt = 0; nt < 4; nt++)
                    acc[mt][nt] = __builtin_amdgcn_mfma_f32_16x16x32_bf16(
                        af[mt], bf_[nt], acc[mt][nt], 0, 0, 0);
        }
        __syncthreads();
    }
    #pragma unroll
    for (int mt = 0; mt < 4; mt++) {
        #pragma unroll
        for (int nt = 0; nt < 4; nt++) {
            #pragma unroll
            for (int r = 0; r < 4; r++) {
                int row = bm + wm + mt * 16 + quad * 4 + r;
                int gn  = bn + wn + nt * 16 + col15;
                float v = acc[mt][nt][r];
                int dir = (gn >= 3072) ? 1 : 0;
                int cc = gn - dir * 3072;
                size_t base = ((size_t)dir * NTOK + row) * DINNER;
                if (cc < DINNER) xi[base + cc] = f2bf(v);
                else             sz[base + cc - DINNER] = f2bf(silu_f(v));
            }
        }
    }
}

// ---------------------------------------------------------------------------
// Kernel 4: depthwise causal conv (k=4) + bias + SiLU.
// bf16 input (ushort8 = 8 channels/thread), fp32 output.
// ---------------------------------------------------------------------------
__global__ void conv_silu(const unsigned short* __restrict__ xi,
                          const float* __restrict__ f_cw, const float* __restrict__ f_cb,
                          const float* __restrict__ b_cw, const float* __restrict__ b_cb,
                          float* __restrict__ xc) {
    const int D8 = DINNER / 8;        // 192
    size_t gid = (size_t)blockIdx.x * 256 + threadIdx.x;
    const size_t total = (size_t)2 * NTOK * D8;
    if (gid >= total) return;
    int d8 = (int)(gid % D8);
    size_t r = gid / D8;              // (dir*2+b)*LSEQ + t
    int t = (int)(r % LSEQ);
    int b = (int)((r / LSEQ) % NB);
    int dir = (int)(r / (LSEQ * NB));
    int d = d8 * 8;
    const float* cw = dir ? b_cw : f_cw;
    const float* cb = dir ? b_cb : f_cb;
    float acc[8], w[4][8];
    #pragma unroll
    for (int j = 0; j < 8; j++) {
        acc[j] = cb[d + j];
        float4 wj = *(const float4*)(cw + (size_t)(d + j) * 4);
        w[0][j] = wj.x; w[1][j] = wj.y; w[2][j] = wj.z; w[3][j] = wj.w;
    }
    size_t xib = ((size_t)dir * NTOK + (size_t)b * LSEQ) * DINNER + d;
    #pragma unroll
    for (int k = 0; k < 4; k++) {
        int u = t - 3 + k;
        if (u < 0) continue;
        int l = dir ? (LSEQ - 1 - u) : u;
        us8 xv = *(const us8*)(xi + xib + (size_t)l * DINNER);
        #pragma unroll
        for (int j = 0; j < 8; j++)
            acc[j] = fmaf(w[k][j], bf2f(xv[j]), acc[j]);
    }
    float* xo = xc + r * DINNER + d;
    float4 o0, o1;
    o0.x = silu_f(acc[0]); o0.y = silu_f(acc[1]); o0.z = silu_f(acc[2]); o0.w = silu_f(acc[3]);
    o1.x = silu_f(acc[4]); o1.y = silu_f(acc[5]); o1.z = silu_f(acc[6]); o1.w = silu_f(acc[7]);
    *(float4*)xo = o0;
    *(float4*)(xo + 4) = o1;
}

// ---------------------------------------------------------------------------
// Kernel 5a: bcdt split-K partials. grid (128 row-blocks, KSPLIT).
// ---------------------------------------------------------------------------
__global__ __launch_bounds__(256)
void bcdt_gemm(const float* __restrict__ xc,
               const float* __restrict__ f_xw,
               const float* __restrict__ b_xw,
               float* __restrict__ part) {
    __shared__ float As[64][33];
    __shared__ float Ws[32 * 33];
    int r0 = blockIdx.x * 64;
    int kc = blockIdx.y;
    const float* xw = (r0 >= NTOK) ? b_xw : f_xw;
    int tid = threadIdx.x;
    int m = tid >> 2, jq = tid & 3;
    float acc[9] = {};
    int kend = kc * 256 + 256;
    for (int k0 = kc * 256; k0 < kend; k0 += 32) {
        for (int i = tid; i < 64 * 32; i += 256) {
            int mm = i >> 5, k = i & 31;
            As[mm][k] = xc[((size_t)r0 + mm) * DINNER + k0 + k];
        }
        for (int i = tid; i < 32 * 33; i += 256)
            Ws[i] = xw[(size_t)k0 * 33 + i];
        __syncthreads();
        #pragma unroll 8
        for (int k = 0; k < 32; k++) {
            float a = As[m][k];
            #pragma unroll
            for (int jj = 0; jj < 9; jj++) {
                int j = jq + jj * 4;
                if (j < 33) acc[jj] = fmaf(a, Ws[k * 33 + j], acc[jj]);
            }
        }
        __syncthreads();
    }
    #pragma unroll
    for (int jj = 0; jj < 9; jj++) {
        int j = jq + jj * 4;
        if (j < 33)
            part[((size_t)kc * (2 * NTOK) + r0 + m) * 33 + j] = acc[jj];
    }
}

// ---------------------------------------------------------------------------
// Kernel 5b: reduce split-K partials.
// ---------------------------------------------------------------------------
__global__ void bcdt_reduce(const float* __restrict__ part, float* __restrict__ bcdt) {
    int i = blockIdx.x * 256 + threadIdx.x;
    const int total = 2 * NTOK * NBCDT;       // 270,336
    if (i >= total) return;
    float s = 0.f;
    #pragma unroll
    for (int kc = 0; kc < KSPLIT; kc++)
        s += part[(size_t)kc * total + i];
    bcdt[i] = s;
}

// ---------------------------------------------------------------------------
// Kernel 6a: chunked scan phase 1 -- one THREAD per channel, h[16] in regs.
// ---------------------------------------------------------------------------
__global__ __launch_bounds__(256)
void scan_p1(const float* __restrict__ xc, const float* __restrict__ bcdt,
             const float* __restrict__ f_dtw, const float* __restrict__ f_dtb,
             const float* __restrict__ f_Alog,
             const float* __restrict__ b_dtw, const float* __restrict__ b_dtb,
             const float* __restrict__ b_Alog,
             float* __restrict__ Pbuf, float* __restrict__ hloc) {
    int tid = threadIdx.x;
    int d = blockIdx.x * 256 + tid;
    int chunk = blockIdx.y;
    int dirb  = blockIdx.z;
    int dir = dirb >> 1;
    const float* dtw  = dir ? b_dtw  : f_dtw;
    const float* dtb  = dir ? b_dtb  : f_dtb;
    const float* Alog = dir ? b_Alog : f_Alog;
    float dtw_d = dtw[d], dtb_d = dtb[d];
    float A[NSTATE], h[NSTATE];
    #pragma unroll
    for (int s = 0; s < NSTATE; s++) {
        float al = fminf(fmaxf(Alog[d * NSTATE + s], -6.f), 6.f);
        A[s] = -__expf(al);
        h[s] = 0.f;
    }
    float Sdt = 0.f;
    size_t rbase = (size_t)dirb * LSEQ + (size_t)chunk * TC;
    const float* bc = bcdt + rbase * NBCDT;
    const float* xp = xc + rbase * DINNER + d;
    for (int t = 0; t < TC; t++) {
        float xv = xp[(size_t)t * DINNER];
        float dt_raw = bc[t * NBCDT];
        float u = fmaf(dt_raw, dtw_d, dtb_d);
        float dt = fmaxf(u, 0.f) + __logf(1.f + __expf(-fabsf(u)));
        Sdt += dt;
        float dtx = dt * xv;
        #pragma unroll
        for (int s = 0; s < NSTATE; s++) {
            float Bv = bc[t * NBCDT + 1 + s];
            h[s] = clip1e4(fmaf(__expf(dt * A[s]), h[s], dtx * Bv));
        }
    }
    size_t base = ((size_t)chunk * 4 + dirb) * ((size_t)DINNER * NSTATE) + (size_t)d * NSTATE;
    #pragma unroll
    for (int s = 0; s < NSTATE; s++) {
        Pbuf[base + s] = __expf(A[s] * Sdt);
        hloc[base + s] = h[s];
    }
}

// ---------------------------------------------------------------------------
// Kernel 6b: phase 2 -- stitch chunk boundary states.
// ---------------------------------------------------------------------------
__global__ void scan_p2(const float* __restrict__ Pbuf, const float* __restrict__ hloc,
                        float* __restrict__ hin) {
    int i = blockIdx.x * 256 + threadIdx.x;
    float h = 0.f;
    const int stride = 4 * DINNER * NSTATE;   // 98304
    for (int c = 0; c < NCHUNK; c++) {
        size_t idx = (size_t)c * stride + i;
        hin[idx] = h;
        h = clip1e4(fmaf(Pbuf[idx], h, hloc[idx]));
    }
}

// ---------------------------------------------------------------------------
// Kernel 6c: phase 3 -- re-run from stitched h_in, thread-per-channel,
// write bf16 yvb [4096][3072].  sz is bf16.
// ---------------------------------------------------------------------------
__global__ __launch_bounds__(256)
void scan_p3(const float* __restrict__ xc, const float* __restrict__ bcdt,
             const unsigned short* __restrict__ sz, const float* __restrict__ hin,
             const float* __restrict__ f_dtw, const float* __restrict__ f_dtb,
             const float* __restrict__ f_Alog, const float* __restrict__ f_D,
             const float* __restrict__ b_dtw, const float* __restrict__ b_dtb,
             const float* __restrict__ b_Alog, const float* __restrict__ b_D,
             unsigned short* __restrict__ yvb) {
    int tid = threadIdx.x;
    int d = blockIdx.x * 256 + tid;
    int chunk = blockIdx.y;
    int dirb  = blockIdx.z;
    int dir = dirb >> 1, b = dirb & 1;
    const float* dtw  = dir ? b_dtw  : f_dtw;
    const float* dtb  = dir ? b_dtb  : f_dtb;
    const float* Alog = dir ? b_Alog : f_Alog;
    const float* Dp   = dir ? b_D    : f_D;
    float dtw_d = dtw[d], dtb_d = dtb[d], D_d = Dp[d];
    float A[NSTATE], h[NSTATE];
    size_t hbase = ((size_t)chunk * 4 + dirb) * ((size_t)DINNER * NSTATE) + (size_t)d * NSTATE;
    #pragma unroll
    for (int s = 0; s < NSTATE; s++) {
        float al = fminf(fmaxf(Alog[d * NSTATE + s], -6.f), 6.f);
        A[s] = -__expf(al);
        h[s] = hin[hbase + s];
    }
    size_t rbase = (size_t)dirb * LSEQ + (size_t)chunk * TC;
    const float* bc = bcdt + rbase * NBCDT;
    const float* xp = xc + rbase * DINNER + d;
    int t0 = chunk * TC;
    for (int t = 0; t < TC; t++) {
        float xv = xp[(size_t)t * DINNER];
        float dt_raw = bc[t * NBCDT];
        float u = fmaf(dt_raw, dtw_d, dtb_d);
        float dt = fmaxf(u, 0.f) + __logf(1.f + __expf(-fabsf(u)));
        float dtx = dt * xv;
        float p = 0.f;
        #pragma unroll
        for (int s = 0; s < NSTATE; s++) {
            float Bv = bc[t * NBCDT + 1 + s];
            float Cv = bc[t * NBCDT + 1 + NSTATE + s];
            h[s] = clip1e4(fmaf(__expf(dt * A[s]), h[s], dtx * Bv));
            p = fmaf(h[s], Cv, p);
        }
        int tt = t0 + t;
        int l = dir ? (LSEQ - 1 - tt) : tt;
        float szv = bf2f(sz[((size_t)dir * NTOK + (size_t)b * LSEQ + l) * DINNER + d]);
        float y = (p + xv * D_d) * szv;
        int row = b * LSEQ + l;
        yvb[(size_t)row * 3072 + dir * DINNER + d] = f2bf(y);
    }
}

// ---------------------------------------------------------------------------
// Kernel 7: output GEMM via MFMA bf16 + residual, async staging + swizzle.
// M=4096, N=768, K=3072.  128x64 tile, BK=64.
// ---------------------------------------------------------------------------
__global__ __launch_bounds__(256)
void gemm_out_mfma(const unsigned short* __restrict__ yvb,
                   const unsigned short* __restrict__ outwT,
                   const float* __restrict__ x,
                   float* __restrict__ out) {
    __shared__ unsigned short Asm[128 * 64];
    __shared__ unsigned short Bsm[64 * 64];
    int tid = threadIdx.x;
    int bm = blockIdx.y * 128;
    int bn = blockIdx.x * 64;
    int wave = tid >> 6, lane = tid & 63;
    int wm = (wave & 1) * 64, wn = (wave >> 1) * 32;
    int col15 = lane & 15, quad = lane >> 4;
    int lrow = lane >> 3;
    int lk   = (((lane & 7) ^ lrow) * 8);      // swizzled global chunk offset
    floatx4 acc[4][2];
    #pragma unroll
    for (int i = 0; i < 4; i++)
        #pragma unroll
        for (int j = 0; j < 2; j++)
            acc[i][j] = (floatx4){0.f, 0.f, 0.f, 0.f};

    int sw = col15 & 7;
    for (int k0 = 0; k0 < 2 * DINNER; k0 += 64) {
        #pragma unroll
        for (int i = 0; i < 4; i++) {
            int r8 = wave * 32 + i * 8;
            ld_lds16(&Asm[r8 * 64], &yvb[(size_t)(bm + r8 + lrow) * 3072 + k0 + lk]);
        }
        #pragma unroll
        for (int i = 0; i < 2; i++) {
            int r8 = wave * 16 + i * 8;
            ld_lds16(&Bsm[r8 * 64], &outwT[(size_t)(bn + r8 + lrow) * 3072 + k0 + lk]);
        }
        __syncthreads();
        #pragma unroll
        for (int k2 = 0; k2 < 2; k2++) {
            bf16x8 af[4], bf_[2];
            int pc = ((k2 * 4 + quad) ^ sw) * 8;
            #pragma unroll
            for (int mt = 0; mt < 4; mt++)
                af[mt] = *(const bf16x8*)(&Asm[(wm + mt * 16 + col15) * 64 + pc]);
            #pragma unroll
            for (int nt = 0; nt < 2; nt++)
                bf_[nt] = *(const bf16x8*)(&Bsm[(wn + nt * 16 + col15) * 64 + pc]);
            #pragma unroll
            for (int mt = 0; mt < 4; mt++)
                #pragma unroll
                for (int nt = 0; nt < 2; nt++)
                    acc[mt][nt] = __builtin_amdgcn_mfma_f32_16x16x32_bf16(
                        af[mt], bf_[nt], acc[mt][nt], 0, 0, 0);
        }
        __syncthreads();
    }
    #pragma unroll
    for (int mt = 0; mt < 4; mt++) {
        #pragma unroll
        for (int nt = 0; nt < 2; nt++) {
            #pragma unroll
            for (int r = 0; r < 4; r++) {
                int row = bm + wm + mt * 16 + quad * 4 + r;
                int gn  = bn + wn + nt * 16 + col15;
                out[(size_t)row * DMODEL + gn] = acc[mt][nt][r] + x[(size_t)row * DMODEL + gn];
            }
        }
    }
}

// ---------------------------------------------------------------------------
extern "C" void kernel_launch(void* const* d_in, const int* in_sizes, int n_in,
                              void* d_out, int out_size, void* d_ws, size_t ws_size,
                              hipStream_t stream) {
    const float* x     = (const float*)d_in[0];
    const float* ln_g  = (const float*)d_in[1];
    const float* ln_b  = (const float*)d_in[2];
    const float* alpha = (const float*)d_in[3];
    const float* f_inw  = (const float*)d_in[4];
    const float* f_cw   = (const float*)d_in[5];
    const float* f_cb   = (const float*)d_in[6];
    const float* f_xw   = (const float*)d_in[7];
    const float* f_dtw  = (const float*)d_in[8];
    const float* f_dtb  = (const float*)d_in[9];
    const float* f_Alog = (const float*)d_in[10];
    const float* f_D    = (const float*)d_in[11];
    const float* f_outw = (const float*)d_in[12];
    const float* b_inw  = (const float*)d_in[13];
    const float* b_cw   = (const float*)d_in[14];
    const float* b_cb   = (const float*)d_in[15];
    const float* b_xw   = (const float*)d_in[16];
    const float* b_dtw  = (const float*)d_in[17];
    const float* b_dtb  = (const float*)d_in[18];
    const float* b_Alog = (const float*)d_in[19];
    const float* b_D    = (const float*)d_in[20];
    const float* b_outw = (const float*)d_in[21];
    float* out = (float*)d_out;

    // Workspace layout (float offsets; total 36.8M floats = 147 MB):
    float* ws = (float*)d_ws;
    const size_t big = (size_t)2 * NTOK * DINNER;             // 12,582,912
    float* r_xnb  = ws;                        // 1,572,864 (xnb bf16); dead after gemm_xz
    float* r_inwT = r_xnb + 1572864;           // 2,359,296 (inwT bf16); dead after gemm_xz
    float* r_outwT= r_inwT + 2359296;          // 1,179,648 (outwT bf16); live till gemm_out
    float* r_xib  = r_outwT + 1179648;         // 6,291,456 (xi bf16); dead after conv -> yvb
    float* r_szb  = r_xib + 6291456;           // 6,291,456 (sz bf16)
    float* xc     = r_szb + 6291456;           // 12,582,912 (fp32)
    float* bcdt   = xc + big;                  // 270,336
    float* hin    = bcdt + 270336;             // 3,145,728
    float* hloc   = hin + 3145728;             // 3,145,728

    unsigned short* xnb   = (unsigned short*)r_xnb;
    unsigned short* inwT  = (unsigned short*)r_inwT;
    unsigned short* outwT = (unsigned short*)r_outwT;
    unsigned short* xib   = (unsigned short*)r_xib;
    unsigned short* szb   = (unsigned short*)r_szb;
    unsigned short* yvb   = (unsigned short*)r_xib;  // alias: xi dead after conv
    float* bcdt_part = r_xnb;                        // 1.62M fl; xnb/inwT dead after gemm_xz
    float* Pbuf = r_xnb;                             // SUM fl, same region (bcdt_part dead)

    // 1. LayerNorm -> bf16
    ln_kernel<<<NTOK, 256, 0, stream>>>(x, ln_g, ln_b, xnb);
    // 2. weight transpose-casts
    {
        dim3 g1(6144 / 32, DMODEL / 32);
        cast_inwT<<<g1, 256, 0, stream>>>(f_inw, b_inw, inwT);
        dim3 g2(DMODEL / 32, 3072 / 32);
        cast_outwT<<<g2, 256, 0, stream>>>(f_outw, b_outw, alpha, outwT);
    }
    // 3. xz GEMM (MFMA, async staging + swizzle, bf16 out)
    {
        dim3 grid(6144 / 128, NTOK / 128);
        gemm_xz_mfma<<<grid, 256, 0, stream>>>(xnb, inwT, xib, szb);
    }
    // 4. conv + silu (bf16 in, fp32 out)
    {
        size_t total = (size_t)2 * NTOK * (DINNER / 8);
        conv_silu<<<(total + 255) / 256, 256, 0, stream>>>(xib, f_cw, f_cb, b_cw, b_cb, xc);
    }
    // 5. bcdt split-K GEMM + reduce
    {
        dim3 g(2 * NTOK / 64, KSPLIT);
        bcdt_gemm<<<g, 256, 0, stream>>>(xc, f_xw, b_xw, bcdt_part);
        bcdt_reduce<<<(2 * NTOK * NBCDT + 255) / 256, 256, 0, stream>>>(bcdt_part, bcdt);
    }
    // 6. chunked scan (thread-per-channel, TC=64)
    {
        dim3 grid1(DINNER / 256, NCHUNK, 4);
        scan_p1<<<grid1, 256, 0, stream>>>(xc, bcdt,
                                           f_dtw, f_dtb, f_Alog,
                                           b_dtw, b_dtb, b_Alog, Pbuf, hloc);
        scan_p2<<<(4 * DINNER * NSTATE) / 256, 256, 0, stream>>>(Pbuf, hloc, hin);
        scan_p3<<<grid1, 256, 0, stream>>>(xc, bcdt, szb, hin,
                                           f_dtw, f_dtb, f_Alog, f_D,
                                           b_dtw, b_dtb, b_Alog, b_D, yvb);
    }
    // 7. out GEMM (MFMA, async staging + swizzle) + residual
    {
        dim3 grid(DMODEL / 64, NTOK / 128);
        gemm_out_mfma<<<grid, 256, 0, stream>>>(yvb, outwT, x, out);
    }
}

// Round 8
// 490.881 us; speedup vs baseline: 1.0527x; 1.0054x over previous
//
#include <hip/hip_runtime.h>
#include <cstddef>
#include <cstdint>

// Problem constants (fixed by reference)
#define DMODEL 768
#define DINNER 1536
#define NSTATE 16
#define LSEQ   2048
#define NB     2
#define NTOK   (NB*LSEQ)        // 4096 tokens
#define NBCDT  33               // 1 + 2*16

// Chunked scan parameters
#define TC     64               // timesteps per chunk
#define NCHUNK (LSEQ/TC)        // 32
#define KSPLIT 6                // bcdt split-K factor (1536/256)

typedef __bf16 bf16x8 __attribute__((ext_vector_type(8)));
typedef float  floatx4 __attribute__((ext_vector_type(4)));
typedef unsigned short us8 __attribute__((ext_vector_type(8)));

__device__ __forceinline__ float silu_f(float x) { return x / (1.f + expf(-x)); }
__device__ __forceinline__ float clip1e4(float x) { return fminf(fmaxf(x, -1e4f), 1e4f); }
__device__ __forceinline__ unsigned short f2bf(float f) {   // RNE float->bf16 bits
    unsigned int u = __float_as_uint(f);
    unsigned int r = u + 0x7fffu + ((u >> 16) & 1u);
    return (unsigned short)(r >> 16);
}
__device__ __forceinline__ float bf2f(unsigned short u) {
    return __uint_as_float((unsigned int)u << 16);
}
// RNE-pack two floats into one dword of bf16 (lo = a, hi = b)
__device__ __forceinline__ unsigned int pack2bf(float a, float b) {
    unsigned int ua = __float_as_uint(a); ua = ua + 0x7fffu + ((ua >> 16) & 1u);
    unsigned int ub = __float_as_uint(b); ub = ub + 0x7fffu + ((ub >> 16) & 1u);
    return (ua >> 16) | (ub & 0xffff0000u);
}
// async global->LDS, 16B per lane; LDS dest = base + lane*16 (wave-uniform base)
__device__ __forceinline__ void ld_lds16(unsigned short* lds, const unsigned short* g) {
    __builtin_amdgcn_global_load_lds(
        (const __attribute__((address_space(1))) unsigned int*)g,
        (__attribute__((address_space(3))) unsigned int*)lds,
        16, 0, 0);
}

// ---------------------------------------------------------------------------
// Kernel 1: LayerNorm -> bf16 output. one block per token row.
// ---------------------------------------------------------------------------
__global__ void ln_kernel(const float* __restrict__ x,
                          const float* __restrict__ g,
                          const float* __restrict__ be,
                          unsigned short* __restrict__ xnb) {
    int row = blockIdx.x;
    int tid = threadIdx.x;
    const float* xr = x + (size_t)row * DMODEL;
    float s = 0.f, ss = 0.f;
    for (int i = tid; i < DMODEL; i += 256) {
        float v = xr[i];
        s += v; ss += v * v;
    }
    for (int o = 32; o >= 1; o >>= 1) {
        s  += __shfl_xor(s,  o, 64);
        ss += __shfl_xor(ss, o, 64);
    }
    __shared__ float sS[4], sSS[4];
    int w = tid >> 6;
    if ((tid & 63) == 0) { sS[w] = s; sSS[w] = ss; }
    __syncthreads();
    s  = sS[0] + sS[1] + sS[2] + sS[3];
    ss = sSS[0] + sSS[1] + sSS[2] + sSS[3];
    float mu = s / DMODEL;
    float var = ss / DMODEL - mu * mu;
    float rstd = rsqrtf(var + 1e-5f);
    unsigned short* xo = xnb + (size_t)row * DMODEL;
    for (int i = tid; i < DMODEL; i += 256)
        xo[i] = f2bf((xr[i] - mu) * rstd * g[i] + be[i]);
}

// ---------------------------------------------------------------------------
// Kernel 2a: transpose-cast in-proj weights: inwT[n][k] (bf16), n in [0,6144)
// ---------------------------------------------------------------------------
__global__ __launch_bounds__(256)
void cast_inwT(const float* __restrict__ fw, const float* __restrict__ bw,
               unsigned short* __restrict__ wT) {
    __shared__ float t[32][33];
    int n0 = blockIdx.x * 32;     // 192 blocks
    int k0 = blockIdx.y * 32;     // 24 blocks
    int tid = threadIdx.x;
    int lr = tid >> 5, lc = tid & 31;
    const float* w = (n0 >= 3072) ? bw : fw;
    int nb = (n0 >= 3072) ? (n0 - 3072) : n0;
    #pragma unroll
    for (int r = 0; r < 4; r++)
        t[r * 8 + lr][lc] = w[(size_t)(k0 + r * 8 + lr) * 3072 + nb + lc];
    __syncthreads();
    #pragma unroll
    for (int r = 0; r < 4; r++)
        wT[(size_t)(n0 + r * 8 + lr) * DMODEL + k0 + lc] = f2bf(t[lc][r * 8 + lr]);
}

// ---------------------------------------------------------------------------
// Kernel 2b: transpose-cast out-proj weights with blend scale folded in.
// ---------------------------------------------------------------------------
__global__ __launch_bounds__(256)
void cast_outwT(const float* __restrict__ fw, const float* __restrict__ bw,
                const float* __restrict__ alpha, unsigned short* __restrict__ wT) {
    __shared__ float t[32][33];
    float a = 1.f / (1.f + expf(-alpha[0]));
    int n0 = blockIdx.x * 32;     // 24 blocks
    int k0 = blockIdx.y * 32;     // 96 blocks
    int tid = threadIdx.x;
    int lr = tid >> 5, lc = tid & 31;
    const float* w = (k0 >= DINNER) ? bw : fw;
    float sc = (k0 >= DINNER) ? (1.f - a) : a;
    int kb = (k0 >= DINNER) ? (k0 - DINNER) : k0;
    #pragma unroll
    for (int r = 0; r < 4; r++)
        t[r * 8 + lr][lc] = w[(size_t)(kb + r * 8 + lr) * DMODEL + n0 + lc];
    __syncthreads();
    #pragma unroll
    for (int r = 0; r < 4; r++)
        wT[(size_t)(n0 + r * 8 + lr) * 3072 + k0 + lc] = f2bf(sc * t[lc][r * 8 + lr]);
}

// ---------------------------------------------------------------------------
// Kernel 3: xz GEMM via MFMA bf16, async LDS staging + XOR-swizzle + LDS-
// bounced coalesced epilogue.  M=4096, N=6144, K=768.  128x128, BK=64.
// ---------------------------------------------------------------------------
__global__ __launch_bounds__(256)
void gemm_xz_mfma(const unsigned short* __restrict__ xnb,
                  const unsigned short* __restrict__ inwT,
                  unsigned short* __restrict__ xi, unsigned short* __restrict__ sz) {
    __shared__ unsigned short SH[2 * 128 * 64];   // A | B staging; reused for C
    unsigned short* Asm = SH;
    unsigned short* Bsm = SH + 128 * 64;
    int tid = threadIdx.x;
    int bm = blockIdx.y * 128;
    int bn = blockIdx.x * 128;
    int wave = tid >> 6, lane = tid & 63;
    int wm = (wave & 1) * 64, wn = (wave >> 1) * 64;
    int col15 = lane & 15, quad = lane >> 4;
    int lrow = lane >> 3;                      // 0..7
    int lk   = (((lane & 7) ^ lrow) * 8);      // swizzled global chunk offset
    floatx4 acc[4][4];
    #pragma unroll
    for (int i = 0; i < 4; i++)
        #pragma unroll
        for (int j = 0; j < 4; j++)
            acc[i][j] = (floatx4){0.f, 0.f, 0.f, 0.f};

    int sw = col15 & 7;
    for (int k0 = 0; k0 < DMODEL; k0 += 64) {
        #pragma unroll
        for (int i = 0; i < 4; i++) {
            int r8 = wave * 32 + i * 8;
            int ra = r8 + lrow;
            ld_lds16(&Asm[r8 * 64], &xnb[(size_t)(bm + ra) * DMODEL + k0 + lk]);
            ld_lds16(&Bsm[r8 * 64], &inwT[(size_t)(bn + ra) * DMODEL + k0 + lk]);
        }
        __syncthreads();
        #pragma unroll
        for (int k2 = 0; k2 < 2; k2++) {
            bf16x8 af[4], bf_[4];
            int pc = ((k2 * 4 + quad) ^ sw) * 8;
            #pragma unroll
            for (int mt = 0; mt < 4; mt++)
                af[mt] = *(const bf16x8*)(&Asm[(wm + mt * 16 + col15) * 64 + pc]);
            #pragma unroll
            for (int nt = 0; nt < 4; nt++)
                bf_[nt] = *(const bf16x8*)(&Bsm[(wn + nt * 16 + col15) * 64 + pc]);
            #pragma unroll
            for (int mt = 0; mt < 4; mt++)
                #pragma unroll
                for (int nt = 0; nt < 4; nt++)
                    acc[mt][nt] = __builtin_amdgcn_mfma_f32_16x16x32_bf16(
                        af[mt], bf_[nt], acc[mt][nt], 0, 0, 0);
        }
        __syncthreads();
    }
    // ---- epilogue: LDS bounce, 32 cols (two 16-col halves) per nt-iter ----
    float* Cst = (float*)SH;                   // [128][36] fp32 = 18.4 KB
    int half = wn >> 6;                        // 0 or 1
    int erow = tid >> 1;
    int g0 = (tid & 1) * 2;
    #pragma unroll
    for (int nt = 0; nt < 4; nt++) {
        __syncthreads();
        #pragma unroll
        for (int mt = 0; mt < 4; mt++)
            #pragma unroll
            for (int r = 0; r < 4; r++)
                Cst[(wm + mt * 16 + quad * 4 + r) * 36 + half * 16 + col15] = acc[mt][nt][r];
        __syncthreads();
        #pragma unroll
        for (int gi = 0; gi < 2; gi++) {
            int g = g0 + gi;
            int hh = g >> 1, c8 = (g & 1) * 8;
            const float* src = &Cst[erow * 36 + hh * 16 + c8];
            float4 v0 = *(const float4*)(src);
            float4 v1 = *(const float4*)(src + 4);
            int gn = bn + hh * 64 + nt * 16 + c8;
            int dir = (gn >= 3072) ? 1 : 0;
            int cc = gn - dir * 3072;
            size_t base = ((size_t)dir * NTOK + (bm + erow)) * DINNER;
            if (cc < DINNER) {
                uint4 pk = { pack2bf(v0.x, v0.y), pack2bf(v0.z, v0.w),
                             pack2bf(v1.x, v1.y), pack2bf(v1.z, v1.w) };
                *(uint4*)(&xi[base + cc]) = pk;
            } else {
                v0.x = silu_f(v0.x); v0.y = silu_f(v0.y);
                v0.z = silu_f(v0.z); v0.w = silu_f(v0.w);
                v1.x = silu_f(v1.x); v1.y = silu_f(v1.y);
                v1.z = silu_f(v1.z); v1.w = silu_f(v1.w);
                uint4 pk = { pack2bf(v0.x, v0.y), pack2bf(v0.z, v0.w),
                             pack2bf(v1.x, v1.y), pack2bf(v1.z, v1.w) };
                *(uint4*)(&sz[base + cc - DINNER]) = pk;
            }
        }
    }
}

// ---------------------------------------------------------------------------
// Kernel 4: depthwise causal conv (k=4) + bias + SiLU.
// bf16 in (ushort8 = 8 channels/thread), bf16 out (only bcdt consumes it).
// ---------------------------------------------------------------------------
__global__ void conv_silu(const unsigned short* __restrict__ xi,
                          const float* __restrict__ f_cw, const float* __restrict__ f_cb,
                          const float* __restrict__ b_cw, const float* __restrict__ b_cb,
                          unsigned short* __restrict__ xcb) {
    const int D8 = DINNER / 8;        // 192
    size_t gid = (size_t)blockIdx.x * 256 + threadIdx.x;
    const size_t total = (size_t)2 * NTOK * D8;
    if (gid >= total) return;
    int d8 = (int)(gid % D8);
    size_t r = gid / D8;              // (dir*2+b)*LSEQ + t
    int t = (int)(r % LSEQ);
    int b = (int)((r / LSEQ) % NB);
    int dir = (int)(r / (LSEQ * NB));
    int d = d8 * 8;
    const float* cw = dir ? b_cw : f_cw;
    const float* cb = dir ? b_cb : f_cb;
    float acc[8], w[4][8];
    #pragma unroll
    for (int j = 0; j < 8; j++) {
        acc[j] = cb[d + j];
        float4 wj = *(const float4*)(cw + (size_t)(d + j) * 4);
        w[0][j] = wj.x; w[1][j] = wj.y; w[2][j] = wj.z; w[3][j] = wj.w;
    }
    size_t xib = ((size_t)dir * NTOK + (size_t)b * LSEQ) * DINNER + d;
    #pragma unroll
    for (int k = 0; k < 4; k++) {
        int u = t - 3 + k;
        if (u < 0) continue;
        int l = dir ? (LSEQ - 1 - u) : u;
        us8 xv = *(const us8*)(xi + xib + (size_t)l * DINNER);
        #pragma unroll
        for (int j = 0; j < 8; j++)
            acc[j] = fmaf(w[k][j], bf2f(xv[j]), acc[j]);
    }
    us8 o;
    #pragma unroll
    for (int j = 0; j < 8; j++) o[j] = f2bf(silu_f(acc[j]));
    *(us8*)(xcb + r * DINNER + d) = o;
}

// ---------------------------------------------------------------------------
// Kernel 5a: bcdt split-K partials from bf16 xc. grid (128 row-blocks, KSPLIT).
// ---------------------------------------------------------------------------
__global__ __launch_bounds__(256)
void bcdt_gemm(const unsigned short* __restrict__ xcb,
               const float* __restrict__ f_xw,
               const float* __restrict__ b_xw,
               float* __restrict__ part) {
    __shared__ float As[64][33];
    __shared__ float Ws[32 * 33];
    int r0 = blockIdx.x * 64;
    int kc = blockIdx.y;
    const float* xw = (r0 >= NTOK) ? b_xw : f_xw;
    int tid = threadIdx.x;
    int m = tid >> 2, jq = tid & 3;
    float acc[9] = {};
    int kend = kc * 256 + 256;
    for (int k0 = kc * 256; k0 < kend; k0 += 32) {
        {
            int mm = tid >> 2, kk = (tid & 3) * 8;
            us8 v = *(const us8*)(&xcb[((size_t)r0 + mm) * DINNER + k0 + kk]);
            #pragma unroll
            for (int j = 0; j < 8; j++) As[mm][kk + j] = bf2f(v[j]);
        }
        for (int i = tid; i < 32 * 33; i += 256)
            Ws[i] = xw[(size_t)k0 * 33 + i];
        __syncthreads();
        #pragma unroll 8
        for (int k = 0; k < 32; k++) {
            float a = As[m][k];
            #pragma unroll
            for (int jj = 0; jj < 9; jj++) {
                int j = jq + jj * 4;
                if (j < 33) acc[jj] = fmaf(a, Ws[k * 33 + j], acc[jj]);
            }
        }
        __syncthreads();
    }
    #pragma unroll
    for (int jj = 0; jj < 9; jj++) {
        int j = jq + jj * 4;
        if (j < 33)
            part[((size_t)kc * (2 * NTOK) + r0 + m) * 33 + j] = acc[jj];
    }
}

// ---------------------------------------------------------------------------
// Kernel 5b: reduce split-K partials.
// ---------------------------------------------------------------------------
__global__ void bcdt_reduce(const float* __restrict__ part, float* __restrict__ bcdt) {
    int i = blockIdx.x * 256 + threadIdx.x;
    const int total = 2 * NTOK * NBCDT;       // 270,336
    if (i >= total) return;
    float s = 0.f;
    #pragma unroll
    for (int kc = 0; kc < KSPLIT; kc++)
        s += part[(size_t)kc * total + i];
    bcdt[i] = s;
}

// ---------------------------------------------------------------------------
// Kernel 6a: scan phase 1 -- thread per channel, h[16] in regs, INLINE CONV
// from bf16 xi via 4-tap rolling window (fp32 math identical to conv_silu).
// ---------------------------------------------------------------------------
__global__ __launch_bounds__(256)
void scan_p1(const unsigned short* __restrict__ xi, const float* __restrict__ bcdt,
             const float* __restrict__ f_cw, const float* __restrict__ f_cb,
             const float* __restrict__ b_cw, const float* __restrict__ b_cb,
             const float* __restrict__ f_dtw, const float* __restrict__ f_dtb,
             const float* __restrict__ f_Alog,
             const float* __restrict__ b_dtw, const float* __restrict__ b_dtb,
             const float* __restrict__ b_Alog,
             float* __restrict__ Pbuf, float* __restrict__ hloc) {
    int tid = threadIdx.x;
    int d = blockIdx.x * 256 + tid;
    int chunk = blockIdx.y;
    int dirb  = blockIdx.z;
    int dir = dirb >> 1, b = dirb & 1;
    const float* dtw  = dir ? b_dtw  : f_dtw;
    const float* dtb  = dir ? b_dtb  : f_dtb;
    const float* Alog = dir ? b_Alog : f_Alog;
    const float* cw   = dir ? b_cw   : f_cw;
    const float* cb   = dir ? b_cb   : f_cb;
    float dtw_d = dtw[d], dtb_d = dtb[d];
    float4 wc = *(const float4*)(cw + (size_t)d * 4);
    float cb_d = cb[d];
    float A[NSTATE], h[NSTATE];
    #pragma unroll
    for (int s = 0; s < NSTATE; s++) {
        float al = fminf(fmaxf(Alog[d * NSTATE + s], -6.f), 6.f);
        A[s] = -__expf(al);
        h[s] = 0.f;
    }
    float Sdt = 0.f;
    int t0 = chunk * TC;
    // xi walk: original index l = t0+t (fwd) or LSEQ-1-(t0+t) (bwd)
    size_t xbase = ((size_t)dir * NTOK + (size_t)b * LSEQ) * DINNER + d;
    long stride = dir ? -(long)DINNER : (long)DINNER;
    int l0 = dir ? (LSEQ - 1 - t0) : t0;
    const unsigned short* xp = xi + xbase + (size_t)l0 * DINNER;
    float xm3 = 0.f, xm2 = 0.f, xm1 = 0.f;
    if (chunk) {
        xm3 = bf2f(*(xp - 3 * stride));
        xm2 = bf2f(*(xp - 2 * stride));
        xm1 = bf2f(*(xp - 1 * stride));
    }
    size_t rbase = (size_t)dirb * LSEQ + (size_t)t0;
    const float* bc = bcdt + rbase * NBCDT;
    for (int t = 0; t < TC; t++) {
        float cur = bf2f(*xp); xp += stride;
        float xv = cb_d;
        xv = fmaf(wc.x, xm3, xv);
        xv = fmaf(wc.y, xm2, xv);
        xv = fmaf(wc.z, xm1, xv);
        xv = fmaf(wc.w, cur, xv);
        xv = silu_f(xv);
        xm3 = xm2; xm2 = xm1; xm1 = cur;
        float dt_raw = bc[t * NBCDT];
        float u = fmaf(dt_raw, dtw_d, dtb_d);
        float dt = fmaxf(u, 0.f) + __logf(1.f + __expf(-fabsf(u)));
        Sdt += dt;
        float dtx = dt * xv;
        #pragma unroll
        for (int s = 0; s < NSTATE; s++) {
            float Bv = bc[t * NBCDT + 1 + s];
            h[s] = clip1e4(fmaf(__expf(dt * A[s]), h[s], dtx * Bv));
        }
    }
    size_t base = ((size_t)chunk * 4 + dirb) * ((size_t)DINNER * NSTATE) + (size_t)d * NSTATE;
    #pragma unroll
    for (int s = 0; s < NSTATE; s++) {
        Pbuf[base + s] = __expf(A[s] * Sdt);
        hloc[base + s] = h[s];
    }
}

// ---------------------------------------------------------------------------
// Kernel 6b: phase 2 -- stitch chunk boundary states.
// ---------------------------------------------------------------------------
__global__ void scan_p2(const float* __restrict__ Pbuf, const float* __restrict__ hloc,
                        float* __restrict__ hin) {
    int i = blockIdx.x * 256 + threadIdx.x;
    float h = 0.f;
    const int stride = 4 * DINNER * NSTATE;   // 98304
    for (int c = 0; c < NCHUNK; c++) {
        size_t idx = (size_t)c * stride + i;
        hin[idx] = h;
        h = clip1e4(fmaf(Pbuf[idx], h, hloc[idx]));
    }
}

// ---------------------------------------------------------------------------
// Kernel 6c: phase 3 -- re-run from stitched h_in, inline conv, write bf16
// yvb [4096][3072] (fwd cols [0,1536), bwd cols [1536,3072) at flipped row).
// ---------------------------------------------------------------------------
__global__ __launch_bounds__(256)
void scan_p3(const unsigned short* __restrict__ xi, const float* __restrict__ bcdt,
             const unsigned short* __restrict__ sz, const float* __restrict__ hin,
             const float* __restrict__ f_cw, const float* __restrict__ f_cb,
             const float* __restrict__ b_cw, const float* __restrict__ b_cb,
             const float* __restrict__ f_dtw, const float* __restrict__ f_dtb,
             const float* __restrict__ f_Alog, const float* __restrict__ f_D,
             const float* __restrict__ b_dtw, const float* __restrict__ b_dtb,
             const float* __restrict__ b_Alog, const float* __restrict__ b_D,
             unsigned short* __restrict__ yvb) {
    int tid = threadIdx.x;
    int d = blockIdx.x * 256 + tid;
    int chunk = blockIdx.y;
    int dirb  = blockIdx.z;
    int dir = dirb >> 1, b = dirb & 1;
    const float* dtw  = dir ? b_dtw  : f_dtw;
    const float* dtb  = dir ? b_dtb  : f_dtb;
    const float* Alog = dir ? b_Alog : f_Alog;
    const float* Dp   = dir ? b_D    : f_D;
    const float* cw   = dir ? b_cw   : f_cw;
    const float* cb   = dir ? b_cb   : f_cb;
    float dtw_d = dtw[d], dtb_d = dtb[d], D_d = Dp[d];
    float4 wc = *(const float4*)(cw + (size_t)d * 4);
    float cb_d = cb[d];
    float A[NSTATE], h[NSTATE];
    size_t hbase = ((size_t)chunk * 4 + dirb) * ((size_t)DINNER * NSTATE) + (size_t)d * NSTATE;
    #pragma unroll
    for (int s = 0; s < NSTATE; s++) {
        float al = fminf(fmaxf(Alog[d * NSTATE + s], -6.f), 6.f);
        A[s] = -__expf(al);
        h[s] = hin[hbase + s];
    }
    int t0 = chunk * TC;
    size_t xbase = ((size_t)dir * NTOK + (size_t)b * LSEQ) * DINNER + d;
    long stride = dir ? -(long)DINNER : (long)DINNER;
    int l0 = dir ? (LSEQ - 1 - t0) : t0;
    const unsigned short* xp = xi + xbase + (size_t)l0 * DINNER;
    const unsigned short* szp = sz + xbase + (size_t)l0 * DINNER;
    unsigned short* yp = yvb + ((size_t)(b * LSEQ + l0)) * 3072 + dir * DINNER + d;
    long ystride = stride * 2;                 // yvb row stride is 3072
    float xm3 = 0.f, xm2 = 0.f, xm1 = 0.f;
    if (chunk) {
        xm3 = bf2f(*(xp - 3 * stride));
        xm2 = bf2f(*(xp - 2 * stride));
        xm1 = bf2f(*(xp - 1 * stride));
    }
    size_t rbase = (size_t)dirb * LSEQ + (size_t)t0;
    const float* bc = bcdt + rbase * NBCDT;
    for (int t = 0; t < TC; t++) {
        float cur = bf2f(*xp); xp += stride;
        float xv = cb_d;
        xv = fmaf(wc.x, xm3, xv);
        xv = fmaf(wc.y, xm2, xv);
        xv = fmaf(wc.z, xm1, xv);
        xv = fmaf(wc.w, cur, xv);
        xv = silu_f(xv);
        xm3 = xm2; xm2 = xm1; xm1 = cur;
        float dt_raw = bc[t * NBCDT];
        float u = fmaf(dt_raw, dtw_d, dtb_d);
        float dt = fmaxf(u, 0.f) + __logf(1.f + __expf(-fabsf(u)));
        float dtx = dt * xv;
        float p = 0.f;
        #pragma unroll
        for (int s = 0; s < NSTATE; s++) {
            float Bv = bc[t * NBCDT + 1 + s];
            float Cv = bc[t * NBCDT + 1 + NSTATE + s];
            h[s] = clip1e4(fmaf(__expf(dt * A[s]), h[s], dtx * Bv));
            p = fmaf(h[s], Cv, p);
        }
        float szv = bf2f(*szp); szp += stride;
        float y = (p + xv * D_d) * szv;
        *yp = f2bf(y); yp += ystride;
    }
}

// ---------------------------------------------------------------------------
// Kernel 7: output GEMM via MFMA bf16 + residual, async staging + swizzle.
// M=4096, N=768, K=3072.  128x64 tile, BK=64.
// ---------------------------------------------------------------------------
__global__ __launch_bounds__(256)
void gemm_out_mfma(const unsigned short* __restrict__ yvb,
                   const unsigned short* __restrict__ outwT,
                   const float* __restrict__ x,
                   float* __restrict__ out) {
    __shared__ unsigned short Asm[128 * 64];
    __shared__ unsigned short Bsm[64 * 64];
    int tid = threadIdx.x;
    int bm = blockIdx.y * 128;
    int bn = blockIdx.x * 64;
    int wave = tid >> 6, lane = tid & 63;
    int wm = (wave & 1) * 64, wn = (wave >> 1) * 32;
    int col15 = lane & 15, quad = lane >> 4;
    int lrow = lane >> 3;
    int lk   = (((lane & 7) ^ lrow) * 8);
    floatx4 acc[4][2];
    #pragma unroll
    for (int i = 0; i < 4; i++)
        #pragma unroll
        for (int j = 0; j < 2; j++)
            acc[i][j] = (floatx4){0.f, 0.f, 0.f, 0.f};

    int sw = col15 & 7;
    for (int k0 = 0; k0 < 2 * DINNER; k0 += 64) {
        #pragma unroll
        for (int i = 0; i < 4; i++) {
            int r8 = wave * 32 + i * 8;
            ld_lds16(&Asm[r8 * 64], &yvb[(size_t)(bm + r8 + lrow) * 3072 + k0 + lk]);
        }
        #pragma unroll
        for (int i = 0; i < 2; i++) {
            int r8 = wave * 16 + i * 8;
            ld_lds16(&Bsm[r8 * 64], &outwT[(size_t)(bn + r8 + lrow) * 3072 + k0 + lk]);
        }
        __syncthreads();
        #pragma unroll
        for (int k2 = 0; k2 < 2; k2++) {
            bf16x8 af[4], bf_[2];
            int pc = ((k2 * 4 + quad) ^ sw) * 8;
            #pragma unroll
            for (int mt = 0; mt < 4; mt++)
                af[mt] = *(const bf16x8*)(&Asm[(wm + mt * 16 + col15) * 64 + pc]);
            #pragma unroll
            for (int nt = 0; nt < 2; nt++)
                bf_[nt] = *(const bf16x8*)(&Bsm[(wn + nt * 16 + col15) * 64 + pc]);
            #pragma unroll
            for (int mt = 0; mt < 4; mt++)
                #pragma unroll
                for (int nt = 0; nt < 2; nt++)
                    acc[mt][nt] = __builtin_amdgcn_mfma_f32_16x16x32_bf16(
                        af[mt], bf_[nt], acc[mt][nt], 0, 0, 0);
        }
        __syncthreads();
    }
    #pragma unroll
    for (int mt = 0; mt < 4; mt++) {
        #pragma unroll
        for (int nt = 0; nt < 2; nt++) {
            #pragma unroll
            for (int r = 0; r < 4; r++) {
                int row = bm + wm + mt * 16 + quad * 4 + r;
                int gn  = bn + wn + nt * 16 + col15;
                out[(size_t)row * DMODEL + gn] = acc[mt][nt][r] + x[(size_t)row * DMODEL + gn];
            }
        }
    }
}

// ---------------------------------------------------------------------------
extern "C" void kernel_launch(void* const* d_in, const int* in_sizes, int n_in,
                              void* d_out, int out_size, void* d_ws, size_t ws_size,
                              hipStream_t stream) {
    const float* x     = (const float*)d_in[0];
    const float* ln_g  = (const float*)d_in[1];
    const float* ln_b  = (const float*)d_in[2];
    const float* alpha = (const float*)d_in[3];
    const float* f_inw  = (const float*)d_in[4];
    const float* f_cw   = (const float*)d_in[5];
    const float* f_cb   = (const float*)d_in[6];
    const float* f_xw   = (const float*)d_in[7];
    const float* f_dtw  = (const float*)d_in[8];
    const float* f_dtb  = (const float*)d_in[9];
    const float* f_Alog = (const float*)d_in[10];
    const float* f_D    = (const float*)d_in[11];
    const float* f_outw = (const float*)d_in[12];
    const float* b_inw  = (const float*)d_in[13];
    const float* b_cw   = (const float*)d_in[14];
    const float* b_cb   = (const float*)d_in[15];
    const float* b_xw   = (const float*)d_in[16];
    const float* b_dtw  = (const float*)d_in[17];
    const float* b_dtb  = (const float*)d_in[18];
    const float* b_Alog = (const float*)d_in[19];
    const float* b_D    = (const float*)d_in[20];
    const float* b_outw = (const float*)d_in[21];
    float* out = (float*)d_out;

    // Workspace layout (float offsets; same 147 MB footprint as rounds 5-7):
    float* ws = (float*)d_ws;
    float* r_xnb  = ws;                        // 1,572,864 (xnb bf16); dead after gemm_xz
    float* r_inwT = r_xnb + 1572864;           // 2,359,296 (inwT bf16); dead after gemm_xz
    float* r_outwT= r_inwT + 2359296;          // 1,179,648 (outwT bf16); live till gemm_out
    float* r_xib  = r_outwT + 1179648;         // 6,291,456 (xi bf16); live through scan_p3
    float* r_szb  = r_xib + 6291456;           // 6,291,456 (sz bf16); live through scan_p3
    float* r_xcb  = r_szb + 6291456;           // 6,291,456 (xcb bf16); dead after bcdt -> yvb
    float* pad    = r_xcb + 6291456;           // 6,291,456 spare (was xc upper half)
    float* bcdt   = pad + 6291456;             // 270,336
    float* hin    = bcdt + 270336;             // 3,145,728
    float* hloc   = hin + 3145728;             // 3,145,728

    unsigned short* xnb   = (unsigned short*)r_xnb;
    unsigned short* inwT  = (unsigned short*)r_inwT;
    unsigned short* outwT = (unsigned short*)r_outwT;
    unsigned short* xib   = (unsigned short*)r_xib;
    unsigned short* szb   = (unsigned short*)r_szb;
    unsigned short* xcb   = (unsigned short*)r_xcb;
    unsigned short* yvb   = (unsigned short*)r_xcb;  // alias: xcb dead after bcdt_gemm
    float* bcdt_part = r_xnb;                        // 1.62M fl; xnb/inwT dead after gemm_xz
    float* Pbuf = r_xnb;                             // 3.15M fl, same region (bcdt_part dead)

    // 1. LayerNorm -> bf16
    ln_kernel<<<NTOK, 256, 0, stream>>>(x, ln_g, ln_b, xnb);
    // 2. weight transpose-casts
    {
        dim3 g1(6144 / 32, DMODEL / 32);
        cast_inwT<<<g1, 256, 0, stream>>>(f_inw, b_inw, inwT);
        dim3 g2(DMODEL / 32, 3072 / 32);
        cast_outwT<<<g2, 256, 0, stream>>>(f_outw, b_outw, alpha, outwT);
    }
    // 3. xz GEMM (MFMA, async staging + swizzle + LDS-bounce epilogue)
    {
        dim3 grid(6144 / 128, NTOK / 128);
        gemm_xz_mfma<<<grid, 256, 0, stream>>>(xnb, inwT, xib, szb);
    }
    // 4. conv + silu (bf16 in, bf16 out; feeds bcdt only)
    {
        size_t total = (size_t)2 * NTOK * (DINNER / 8);
        conv_silu<<<(total + 255) / 256, 256, 0, stream>>>(xib, f_cw, f_cb, b_cw, b_cb, xcb);
    }
    // 5. bcdt split-K GEMM + reduce
    {
        dim3 g(2 * NTOK / 64, KSPLIT);
        bcdt_gemm<<<g, 256, 0, stream>>>(xcb, f_xw, b_xw, bcdt_part);
        bcdt_reduce<<<(2 * NTOK * NBCDT + 255) / 256, 256, 0, stream>>>(bcdt_part, bcdt);
    }
    // 6. chunked scan (thread-per-channel, inline conv from xib)
    {
        dim3 grid1(DINNER / 256, NCHUNK, 4);
        scan_p1<<<grid1, 256, 0, stream>>>(xib, bcdt, f_cw, f_cb, b_cw, b_cb,
                                           f_dtw, f_dtb, f_Alog,
                                           b_dtw, b_dtb, b_Alog, Pbuf, hloc);
        scan_p2<<<(4 * DINNER * NSTATE) / 256, 256, 0, stream>>>(Pbuf, hloc, hin);
        scan_p3<<<grid1, 256, 0, stream>>>(xib, bcdt, szb, hin,
                                           f_cw, f_cb, b_cw, b_cb,
                                           f_dtw, f_dtb, f_Alog, f_D,
                                           b_dtw, b_dtb, b_Alog, b_D, yvb);
    }
    // 7. out GEMM (MFMA, async staging + swizzle) + residual
    {
        dim3 grid(DMODEL / 64, NTOK / 128);
        gemm_out_mfma<<<grid, 256, 0, stream>>>(yvb, outwT, x, out);
    }
}

// Round 9
// 444.914 us; speedup vs baseline: 1.1615x; 1.1033x over previous
//
#include <hip/hip_runtime.h>
#include <cstddef>
#include <cstdint>

// Problem constants (fixed by reference)
#define DMODEL 768
#define DINNER 1536
#define NSTATE 16
#define LSEQ   2048
#define NB     2
#define NTOK   (NB*LSEQ)        // 4096 tokens
#define NBCDT  33               // 1 + 2*16

// Chunked scan parameters
#define TC     32               // timesteps per chunk (occupancy: 1536 blocks)
#define NCHUNK (LSEQ/TC)        // 64
#define KSPLIT 6                // bcdt split-K factor (1536/256)

typedef __bf16 bf16x8 __attribute__((ext_vector_type(8)));
typedef float  floatx4 __attribute__((ext_vector_type(4)));
typedef unsigned short us8 __attribute__((ext_vector_type(8)));

__device__ __forceinline__ float silu_f(float x) { return x / (1.f + expf(-x)); }
__device__ __forceinline__ float clip1e4(float x) {
    return __builtin_amdgcn_fmed3f(x, -1e4f, 1e4f);   // single v_med3_f32
}
__device__ __forceinline__ unsigned short f2bf(float f) {   // RNE float->bf16 bits
    unsigned int u = __float_as_uint(f);
    unsigned int r = u + 0x7fffu + ((u >> 16) & 1u);
    return (unsigned short)(r >> 16);
}
__device__ __forceinline__ float bf2f(unsigned short u) {
    return __uint_as_float((unsigned int)u << 16);
}
// RNE-pack two floats into one dword of bf16 (lo = a, hi = b)
__device__ __forceinline__ unsigned int pack2bf(float a, float b) {
    unsigned int ua = __float_as_uint(a); ua = ua + 0x7fffu + ((ua >> 16) & 1u);
    unsigned int ub = __float_as_uint(b); ub = ub + 0x7fffu + ((ub >> 16) & 1u);
    return (ua >> 16) | (ub & 0xffff0000u);
}
// async global->LDS, 16B per lane; LDS dest = base + lane*16 (wave-uniform base)
__device__ __forceinline__ void ld_lds16(unsigned short* lds, const unsigned short* g) {
    __builtin_amdgcn_global_load_lds(
        (const __attribute__((address_space(1))) unsigned int*)g,
        (__attribute__((address_space(3))) unsigned int*)lds,
        16, 0, 0);
}

// ---------------------------------------------------------------------------
// Kernel 1: LayerNorm -> bf16 output. one block per token row.
// ---------------------------------------------------------------------------
__global__ void ln_kernel(const float* __restrict__ x,
                          const float* __restrict__ g,
                          const float* __restrict__ be,
                          unsigned short* __restrict__ xnb) {
    int row = blockIdx.x;
    int tid = threadIdx.x;
    const float* xr = x + (size_t)row * DMODEL;
    float s = 0.f, ss = 0.f;
    for (int i = tid; i < DMODEL; i += 256) {
        float v = xr[i];
        s += v; ss += v * v;
    }
    for (int o = 32; o >= 1; o >>= 1) {
        s  += __shfl_xor(s,  o, 64);
        ss += __shfl_xor(ss, o, 64);
    }
    __shared__ float sS[4], sSS[4];
    int w = tid >> 6;
    if ((tid & 63) == 0) { sS[w] = s; sSS[w] = ss; }
    __syncthreads();
    s  = sS[0] + sS[1] + sS[2] + sS[3];
    ss = sSS[0] + sSS[1] + sSS[2] + sSS[3];
    float mu = s / DMODEL;
    float var = ss / DMODEL - mu * mu;
    float rstd = rsqrtf(var + 1e-5f);
    unsigned short* xo = xnb + (size_t)row * DMODEL;
    for (int i = tid; i < DMODEL; i += 256)
        xo[i] = f2bf((xr[i] - mu) * rstd * g[i] + be[i]);
}

// ---------------------------------------------------------------------------
// Kernel 2a: transpose-cast in-proj weights: inwT[n][k] (bf16), n in [0,6144)
// ---------------------------------------------------------------------------
__global__ __launch_bounds__(256)
void cast_inwT(const float* __restrict__ fw, const float* __restrict__ bw,
               unsigned short* __restrict__ wT) {
    __shared__ float t[32][33];
    int n0 = blockIdx.x * 32;     // 192 blocks
    int k0 = blockIdx.y * 32;     // 24 blocks
    int tid = threadIdx.x;
    int lr = tid >> 5, lc = tid & 31;
    const float* w = (n0 >= 3072) ? bw : fw;
    int nb = (n0 >= 3072) ? (n0 - 3072) : n0;
    #pragma unroll
    for (int r = 0; r < 4; r++)
        t[r * 8 + lr][lc] = w[(size_t)(k0 + r * 8 + lr) * 3072 + nb + lc];
    __syncthreads();
    #pragma unroll
    for (int r = 0; r < 4; r++)
        wT[(size_t)(n0 + r * 8 + lr) * DMODEL + k0 + lc] = f2bf(t[lc][r * 8 + lr]);
}

// ---------------------------------------------------------------------------
// Kernel 2b: transpose-cast out-proj weights with blend scale folded in.
// ---------------------------------------------------------------------------
__global__ __launch_bounds__(256)
void cast_outwT(const float* __restrict__ fw, const float* __restrict__ bw,
                const float* __restrict__ alpha, unsigned short* __restrict__ wT) {
    __shared__ float t[32][33];
    float a = 1.f / (1.f + expf(-alpha[0]));
    int n0 = blockIdx.x * 32;     // 24 blocks
    int k0 = blockIdx.y * 32;     // 96 blocks
    int tid = threadIdx.x;
    int lr = tid >> 5, lc = tid & 31;
    const float* w = (k0 >= DINNER) ? bw : fw;
    float sc = (k0 >= DINNER) ? (1.f - a) : a;
    int kb = (k0 >= DINNER) ? (k0 - DINNER) : k0;
    #pragma unroll
    for (int r = 0; r < 4; r++)
        t[r * 8 + lr][lc] = w[(size_t)(kb + r * 8 + lr) * DMODEL + n0 + lc];
    __syncthreads();
    #pragma unroll
    for (int r = 0; r < 4; r++)
        wT[(size_t)(n0 + r * 8 + lr) * 3072 + k0 + lc] = f2bf(sc * t[lc][r * 8 + lr]);
}

// ---------------------------------------------------------------------------
// Kernel 3: xz GEMM via MFMA bf16, async LDS staging + XOR-swizzle + LDS-
// bounced coalesced epilogue.  M=4096, N=6144, K=768.  128x128, BK=64.
// ---------------------------------------------------------------------------
__global__ __launch_bounds__(256)
void gemm_xz_mfma(const unsigned short* __restrict__ xnb,
                  const unsigned short* __restrict__ inwT,
                  unsigned short* __restrict__ xi, unsigned short* __restrict__ sz) {
    __shared__ unsigned short SH[2 * 128 * 64];   // A | B staging; reused for C
    unsigned short* Asm = SH;
    unsigned short* Bsm = SH + 128 * 64;
    int tid = threadIdx.x;
    int bm = blockIdx.y * 128;
    int bn = blockIdx.x * 128;
    int wave = tid >> 6, lane = tid & 63;
    int wm = (wave & 1) * 64, wn = (wave >> 1) * 64;
    int col15 = lane & 15, quad = lane >> 4;
    int lrow = lane >> 3;                      // 0..7
    int lk   = (((lane & 7) ^ lrow) * 8);      // swizzled global chunk offset
    floatx4 acc[4][4];
    #pragma unroll
    for (int i = 0; i < 4; i++)
        #pragma unroll
        for (int j = 0; j < 4; j++)
            acc[i][j] = (floatx4){0.f, 0.f, 0.f, 0.f};

    int sw = col15 & 7;
    for (int k0 = 0; k0 < DMODEL; k0 += 64) {
        #pragma unroll
        for (int i = 0; i < 4; i++) {
            int r8 = wave * 32 + i * 8;
            int ra = r8 + lrow;
            ld_lds16(&Asm[r8 * 64], &xnb[(size_t)(bm + ra) * DMODEL + k0 + lk]);
            ld_lds16(&Bsm[r8 * 64], &inwT[(size_t)(bn + ra) * DMODEL + k0 + lk]);
        }
        __syncthreads();
        #pragma unroll
        for (int k2 = 0; k2 < 2; k2++) {
            bf16x8 af[4], bf_[4];
            int pc = ((k2 * 4 + quad) ^ sw) * 8;
            #pragma unroll
            for (int mt = 0; mt < 4; mt++)
                af[mt] = *(const bf16x8*)(&Asm[(wm + mt * 16 + col15) * 64 + pc]);
            #pragma unroll
            for (int nt = 0; nt < 4; nt++)
                bf_[nt] = *(const bf16x8*)(&Bsm[(wn + nt * 16 + col15) * 64 + pc]);
            #pragma unroll
            for (int mt = 0; mt < 4; mt++)
                #pragma unroll
                for (int nt = 0; nt < 4; nt++)
                    acc[mt][nt] = __builtin_amdgcn_mfma_f32_16x16x32_bf16(
                        af[mt], bf_[nt], acc[mt][nt], 0, 0, 0);
        }
        __syncthreads();
    }
    // ---- epilogue: LDS bounce, coalesced bf16 stores ----
    float* Cst = (float*)SH;                   // [128][36] fp32
    int half = wn >> 6;
    int erow = tid >> 1;
    int g0 = (tid & 1) * 2;
    #pragma unroll
    for (int nt = 0; nt < 4; nt++) {
        __syncthreads();
        #pragma unroll
        for (int mt = 0; mt < 4; mt++)
            #pragma unroll
            for (int r = 0; r < 4; r++)
                Cst[(wm + mt * 16 + quad * 4 + r) * 36 + half * 16 + col15] = acc[mt][nt][r];
        __syncthreads();
        #pragma unroll
        for (int gi = 0; gi < 2; gi++) {
            int g = g0 + gi;
            int hh = g >> 1, c8 = (g & 1) * 8;
            const float* src = &Cst[erow * 36 + hh * 16 + c8];
            float4 v0 = *(const float4*)(src);
            float4 v1 = *(const float4*)(src + 4);
            int gn = bn + hh * 64 + nt * 16 + c8;
            int dir = (gn >= 3072) ? 1 : 0;
            int cc = gn - dir * 3072;
            size_t base = ((size_t)dir * NTOK + (bm + erow)) * DINNER;
            if (cc < DINNER) {
                uint4 pk = { pack2bf(v0.x, v0.y), pack2bf(v0.z, v0.w),
                             pack2bf(v1.x, v1.y), pack2bf(v1.z, v1.w) };
                *(uint4*)(&xi[base + cc]) = pk;
            } else {
                v0.x = silu_f(v0.x); v0.y = silu_f(v0.y);
                v0.z = silu_f(v0.z); v0.w = silu_f(v0.w);
                v1.x = silu_f(v1.x); v1.y = silu_f(v1.y);
                v1.z = silu_f(v1.z); v1.w = silu_f(v1.w);
                uint4 pk = { pack2bf(v0.x, v0.y), pack2bf(v0.z, v0.w),
                             pack2bf(v1.x, v1.y), pack2bf(v1.z, v1.w) };
                *(uint4*)(&sz[base + cc - DINNER]) = pk;
            }
        }
    }
}

// ---------------------------------------------------------------------------
// Kernel 4: FUSED conv + bcdt split-K GEMM.  grid (128 row-blocks, KSPLIT).
// Stages 67x32 bf16 xi rows, conv+SiLU into fp32 A-tile in LDS, then GEMM.
// part[kc][row][j] = sum over k in [kc*256, kc*256+256).
// ---------------------------------------------------------------------------
__global__ __launch_bounds__(256)
void bcdt_conv_gemm(const unsigned short* __restrict__ xi,
                    const float* __restrict__ f_cw, const float* __restrict__ f_cb,
                    const float* __restrict__ b_cw, const float* __restrict__ b_cb,
                    const float* __restrict__ f_xw, const float* __restrict__ b_xw,
                    float* __restrict__ part) {
    __shared__ unsigned short Xs[67 * 32];
    __shared__ float As[64][33];
    __shared__ float Ws[32 * 33];
    __shared__ float Wc[32][4];
    __shared__ float Cb[32];
    int r0 = blockIdx.x * 64;
    int kc = blockIdx.y;
    int dirb = r0 >> 11;              // r0 / 2048
    int dir = dirb >> 1, b = dirb & 1;
    int t0 = r0 & 2047;
    const float* xw = dir ? b_xw : f_xw;
    const float* cw = dir ? b_cw : f_cw;
    const float* cb = dir ? b_cb : f_cb;
    int tid = threadIdx.x;
    int m = tid >> 2, jq = tid & 3;
    float acc[9] = {};
    size_t xibase = ((size_t)dir * NTOK + (size_t)b * LSEQ) * DINNER;
    int kend = kc * 256 + 256;
    for (int k0 = kc * 256; k0 < kend; k0 += 32) {
        if (tid < 32) {
            float4 w4 = *(const float4*)(cw + (size_t)(k0 + tid) * 4);
            Wc[tid][0] = w4.x; Wc[tid][1] = w4.y; Wc[tid][2] = w4.z; Wc[tid][3] = w4.w;
            Cb[tid] = cb[k0 + tid];
        }
        // stage xi rows u = t0-3 .. t0+63 (67 rows) x 32 channels (us2/thread)
        for (int j = tid; j < 67 * 16; j += 256) {
            int row = j >> 4, c2 = (j & 15) * 2;
            int u = t0 - 3 + row;
            unsigned int v = 0;
            if (u >= 0) {
                int l = dir ? (LSEQ - 1 - u) : u;
                v = *(const unsigned int*)(&xi[xibase + (size_t)l * DINNER + k0 + c2]);
            }
            *(unsigned int*)(&Xs[row * 32 + c2]) = v;
        }
        for (int i = tid; i < 32 * 33; i += 256)
            Ws[i] = xw[(size_t)k0 * 33 + i];
        __syncthreads();
        // conv + silu -> fp32 A tile (xc[t] uses stage rows t..t+3)
        for (int j = tid; j < 64 * 32; j += 256) {
            int t = j >> 5, ch = j & 31;
            float a = Cb[ch];
            #pragma unroll
            for (int k = 0; k < 4; k++)
                a = fmaf(Wc[ch][k], bf2f(Xs[(t + k) * 32 + ch]), a);
            As[t][ch] = silu_f(a);
        }
        __syncthreads();
        #pragma unroll 8
        for (int k = 0; k < 32; k++) {
            float a = As[m][k];
            #pragma unroll
            for (int jj = 0; jj < 9; jj++) {
                int j = jq + jj * 4;
                if (j < 33) acc[jj] = fmaf(a, Ws[k * 33 + j], acc[jj]);
            }
        }
        __syncthreads();
    }
    #pragma unroll
    for (int jj = 0; jj < 9; jj++) {
        int j = jq + jj * 4;
        if (j < 33)
            part[((size_t)kc * (2 * NTOK) + r0 + m) * 33 + j] = acc[jj];
    }
}

// ---------------------------------------------------------------------------
// Kernel 5: reduce split-K partials.
// ---------------------------------------------------------------------------
__global__ void bcdt_reduce(const float* __restrict__ part, float* __restrict__ bcdt) {
    int i = blockIdx.x * 256 + threadIdx.x;
    const int total = 2 * NTOK * NBCDT;       // 270,336
    if (i >= total) return;
    float s = 0.f;
    #pragma unroll
    for (int kc = 0; kc < KSPLIT; kc++)
        s += part[(size_t)kc * total + i];
    bcdt[i] = s;
}

// ---------------------------------------------------------------------------
// Kernel 6a: scan phase 1 -- thread per channel, h[16] in regs, inline conv
// from bf16 xi via 4-tap rolling window.
// ---------------------------------------------------------------------------
__global__ __launch_bounds__(256)
void scan_p1(const unsigned short* __restrict__ xi, const float* __restrict__ bcdt,
             const float* __restrict__ f_cw, const float* __restrict__ f_cb,
             const float* __restrict__ b_cw, const float* __restrict__ b_cb,
             const float* __restrict__ f_dtw, const float* __restrict__ f_dtb,
             const float* __restrict__ f_Alog,
             const float* __restrict__ b_dtw, const float* __restrict__ b_dtb,
             const float* __restrict__ b_Alog,
             float* __restrict__ Pbuf, float* __restrict__ hloc) {
    int tid = threadIdx.x;
    int d = blockIdx.x * 256 + tid;
    int chunk = blockIdx.y;
    int dirb  = blockIdx.z;
    int dir = dirb >> 1, b = dirb & 1;
    const float* dtw  = dir ? b_dtw  : f_dtw;
    const float* dtb  = dir ? b_dtb  : f_dtb;
    const float* Alog = dir ? b_Alog : f_Alog;
    const float* cw   = dir ? b_cw   : f_cw;
    const float* cb   = dir ? b_cb   : f_cb;
    float dtw_d = dtw[d], dtb_d = dtb[d];
    float4 wc = *(const float4*)(cw + (size_t)d * 4);
    float cb_d = cb[d];
    float A[NSTATE], h[NSTATE];
    #pragma unroll
    for (int s = 0; s < NSTATE; s++) {
        float al = fminf(fmaxf(Alog[d * NSTATE + s], -6.f), 6.f);
        A[s] = -__expf(al);
        h[s] = 0.f;
    }
    float Sdt = 0.f;
    int t0 = chunk * TC;
    size_t xbase = ((size_t)dir * NTOK + (size_t)b * LSEQ) * DINNER + d;
    long stride = dir ? -(long)DINNER : (long)DINNER;
    int l0 = dir ? (LSEQ - 1 - t0) : t0;
    const unsigned short* xp = xi + xbase + (size_t)l0 * DINNER;
    float xm3 = 0.f, xm2 = 0.f, xm1 = 0.f;
    if (chunk) {
        xm3 = bf2f(*(xp - 3 * stride));
        xm2 = bf2f(*(xp - 2 * stride));
        xm1 = bf2f(*(xp - 1 * stride));
    }
    size_t rbase = (size_t)dirb * LSEQ + (size_t)t0;
    const float* bc = bcdt + rbase * NBCDT;
    for (int t = 0; t < TC; t++) {
        float cur = bf2f(*xp); xp += stride;
        float xv = cb_d;
        xv = fmaf(wc.x, xm3, xv);
        xv = fmaf(wc.y, xm2, xv);
        xv = fmaf(wc.z, xm1, xv);
        xv = fmaf(wc.w, cur, xv);
        xv = silu_f(xv);
        xm3 = xm2; xm2 = xm1; xm1 = cur;
        float dt_raw = bc[t * NBCDT];
        float u = fmaf(dt_raw, dtw_d, dtb_d);
        float dt = fmaxf(u, 0.f) + __logf(1.f + __expf(-fabsf(u)));
        Sdt += dt;
        float dtx = dt * xv;
        #pragma unroll
        for (int s = 0; s < NSTATE; s++) {
            float Bv = bc[t * NBCDT + 1 + s];
            h[s] = clip1e4(fmaf(__expf(dt * A[s]), h[s], dtx * Bv));
        }
    }
    size_t base = ((size_t)chunk * 4 + dirb) * ((size_t)DINNER * NSTATE) + (size_t)d * NSTATE;
    #pragma unroll
    for (int s = 0; s < NSTATE; s++) {
        Pbuf[base + s] = __expf(A[s] * Sdt);
        hloc[base + s] = h[s];
    }
}

// ---------------------------------------------------------------------------
// Kernel 6b: phase 2 -- stitch chunk boundary states.
// ---------------------------------------------------------------------------
__global__ void scan_p2(const float* __restrict__ Pbuf, const float* __restrict__ hloc,
                        float* __restrict__ hin) {
    int i = blockIdx.x * 256 + threadIdx.x;
    float h = 0.f;
    const int stride = 4 * DINNER * NSTATE;   // 98304
    for (int c = 0; c < NCHUNK; c++) {
        size_t idx = (size_t)c * stride + i;
        hin[idx] = h;
        h = clip1e4(fmaf(Pbuf[idx], h, hloc[idx]));
    }
}

// ---------------------------------------------------------------------------
// Kernel 6c: phase 3 -- re-run from stitched h_in, inline conv, write bf16
// yvb [4096][3072] (fwd cols [0,1536), bwd cols [1536,3072) at flipped row).
// ---------------------------------------------------------------------------
__global__ __launch_bounds__(256)
void scan_p3(const unsigned short* __restrict__ xi, const float* __restrict__ bcdt,
             const unsigned short* __restrict__ sz, const float* __restrict__ hin,
             const float* __restrict__ f_cw, const float* __restrict__ f_cb,
             const float* __restrict__ b_cw, const float* __restrict__ b_cb,
             const float* __restrict__ f_dtw, const float* __restrict__ f_dtb,
             const float* __restrict__ f_Alog, const float* __restrict__ f_D,
             const float* __restrict__ b_dtw, const float* __restrict__ b_dtb,
             const float* __restrict__ b_Alog, const float* __restrict__ b_D,
             unsigned short* __restrict__ yvb) {
    int tid = threadIdx.x;
    int d = blockIdx.x * 256 + tid;
    int chunk = blockIdx.y;
    int dirb  = blockIdx.z;
    int dir = dirb >> 1, b = dirb & 1;
    const float* dtw  = dir ? b_dtw  : f_dtw;
    const float* dtb  = dir ? b_dtb  : f_dtb;
    const float* Alog = dir ? b_Alog : f_Alog;
    const float* Dp   = dir ? b_D    : f_D;
    const float* cw   = dir ? b_cw   : f_cw;
    const float* cb   = dir ? b_cb   : f_cb;
    float dtw_d = dtw[d], dtb_d = dtb[d], D_d = Dp[d];
    float4 wc = *(const float4*)(cw + (size_t)d * 4);
    float cb_d = cb[d];
    float A[NSTATE], h[NSTATE];
    size_t hbase = ((size_t)chunk * 4 + dirb) * ((size_t)DINNER * NSTATE) + (size_t)d * NSTATE;
    #pragma unroll
    for (int s = 0; s < NSTATE; s++) {
        float al = fminf(fmaxf(Alog[d * NSTATE + s], -6.f), 6.f);
        A[s] = -__expf(al);
        h[s] = hin[hbase + s];
    }
    int t0 = chunk * TC;
    size_t xbase = ((size_t)dir * NTOK + (size_t)b * LSEQ) * DINNER + d;
    long stride = dir ? -(long)DINNER : (long)DINNER;
    int l0 = dir ? (LSEQ - 1 - t0) : t0;
    const unsigned short* xp = xi + xbase + (size_t)l0 * DINNER;
    const unsigned short* szp = sz + xbase + (size_t)l0 * DINNER;
    unsigned short* yp = yvb + ((size_t)(b * LSEQ + l0)) * 3072 + dir * DINNER + d;
    long ystride = stride * 2;                 // yvb row stride is 3072
    float xm3 = 0.f, xm2 = 0.f, xm1 = 0.f;
    if (chunk) {
        xm3 = bf2f(*(xp - 3 * stride));
        xm2 = bf2f(*(xp - 2 * stride));
        xm1 = bf2f(*(xp - 1 * stride));
    }
    size_t rbase = (size_t)dirb * LSEQ + (size_t)t0;
    const float* bc = bcdt + rbase * NBCDT;
    for (int t = 0; t < TC; t++) {
        float cur = bf2f(*xp); xp += stride;
        float xv = cb_d;
        xv = fmaf(wc.x, xm3, xv);
        xv = fmaf(wc.y, xm2, xv);
        xv = fmaf(wc.z, xm1, xv);
        xv = fmaf(wc.w, cur, xv);
        xv = silu_f(xv);
        xm3 = xm2; xm2 = xm1; xm1 = cur;
        float dt_raw = bc[t * NBCDT];
        float u = fmaf(dt_raw, dtw_d, dtb_d);
        float dt = fmaxf(u, 0.f) + __logf(1.f + __expf(-fabsf(u)));
        float dtx = dt * xv;
        float p = 0.f;
        #pragma unroll
        for (int s = 0; s < NSTATE; s++) {
            float Bv = bc[t * NBCDT + 1 + s];
            float Cv = bc[t * NBCDT + 1 + NSTATE + s];
            h[s] = clip1e4(fmaf(__expf(dt * A[s]), h[s], dtx * Bv));
            p = fmaf(h[s], Cv, p);
        }
        float szv = bf2f(*szp); szp += stride;
        float y = (p + xv * D_d) * szv;
        *yp = f2bf(y); yp += ystride;
    }
}

// ---------------------------------------------------------------------------
// Kernel 7: output GEMM via MFMA bf16 + residual, async staging + swizzle.
// M=4096, N=768, K=3072.  128x64 tile, BK=64.
// ---------------------------------------------------------------------------
__global__ __launch_bounds__(256)
void gemm_out_mfma(const unsigned short* __restrict__ yvb,
                   const unsigned short* __restrict__ outwT,
                   const float* __restrict__ x,
                   float* __restrict__ out) {
    __shared__ unsigned short Asm[128 * 64];
    __shared__ unsigned short Bsm[64 * 64];
    int tid = threadIdx.x;
    int bm = blockIdx.y * 128;
    int bn = blockIdx.x * 64;
    int wave = tid >> 6, lane = tid & 63;
    int wm = (wave & 1) * 64, wn = (wave >> 1) * 32;
    int col15 = lane & 15, quad = lane >> 4;
    int lrow = lane >> 3;
    int lk   = (((lane & 7) ^ lrow) * 8);
    floatx4 acc[4][2];
    #pragma unroll
    for (int i = 0; i < 4; i++)
        #pragma unroll
        for (int j = 0; j < 2; j++)
            acc[i][j] = (floatx4){0.f, 0.f, 0.f, 0.f};

    int sw = col15 & 7;
    for (int k0 = 0; k0 < 2 * DINNER; k0 += 64) {
        #pragma unroll
        for (int i = 0; i < 4; i++) {
            int r8 = wave * 32 + i * 8;
            ld_lds16(&Asm[r8 * 64], &yvb[(size_t)(bm + r8 + lrow) * 3072 + k0 + lk]);
        }
        #pragma unroll
        for (int i = 0; i < 2; i++) {
            int r8 = wave * 16 + i * 8;
            ld_lds16(&Bsm[r8 * 64], &outwT[(size_t)(bn + r8 + lrow) * 3072 + k0 + lk]);
        }
        __syncthreads();
        #pragma unroll
        for (int k2 = 0; k2 < 2; k2++) {
            bf16x8 af[4], bf_[2];
            int pc = ((k2 * 4 + quad) ^ sw) * 8;
            #pragma unroll
            for (int mt = 0; mt < 4; mt++)
                af[mt] = *(const bf16x8*)(&Asm[(wm + mt * 16 + col15) * 64 + pc]);
            #pragma unroll
            for (int nt = 0; nt < 2; nt++)
                bf_[nt] = *(const bf16x8*)(&Bsm[(wn + nt * 16 + col15) * 64 + pc]);
            #pragma unroll
            for (int mt = 0; mt < 4; mt++)
                #pragma unroll
                for (int nt = 0; nt < 2; nt++)
                    acc[mt][nt] = __builtin_amdgcn_mfma_f32_16x16x32_bf16(
                        af[mt], bf_[nt], acc[mt][nt], 0, 0, 0);
        }
        __syncthreads();
    }
    #pragma unroll
    for (int mt = 0; mt < 4; mt++) {
        #pragma unroll
        for (int nt = 0; nt < 2; nt++) {
            #pragma unroll
            for (int r = 0; r < 4; r++) {
                int row = bm + wm + mt * 16 + quad * 4 + r;
                int gn  = bn + wn + nt * 16 + col15;
                out[(size_t)row * DMODEL + gn] = acc[mt][nt][r] + x[(size_t)row * DMODEL + gn];
            }
        }
    }
}

// ---------------------------------------------------------------------------
extern "C" void kernel_launch(void* const* d_in, const int* in_sizes, int n_in,
                              void* d_out, int out_size, void* d_ws, size_t ws_size,
                              hipStream_t stream) {
    const float* x     = (const float*)d_in[0];
    const float* ln_g  = (const float*)d_in[1];
    const float* ln_b  = (const float*)d_in[2];
    const float* alpha = (const float*)d_in[3];
    const float* f_inw  = (const float*)d_in[4];
    const float* f_cw   = (const float*)d_in[5];
    const float* f_cb   = (const float*)d_in[6];
    const float* f_xw   = (const float*)d_in[7];
    const float* f_dtw  = (const float*)d_in[8];
    const float* f_dtb  = (const float*)d_in[9];
    const float* f_Alog = (const float*)d_in[10];
    const float* f_D    = (const float*)d_in[11];
    const float* f_outw = (const float*)d_in[12];
    const float* b_inw  = (const float*)d_in[13];
    const float* b_cw   = (const float*)d_in[14];
    const float* b_cb   = (const float*)d_in[15];
    const float* b_xw   = (const float*)d_in[16];
    const float* b_dtw  = (const float*)d_in[17];
    const float* b_dtb  = (const float*)d_in[18];
    const float* b_Alog = (const float*)d_in[19];
    const float* b_D    = (const float*)d_in[20];
    const float* b_outw = (const float*)d_in[21];
    float* out = (float*)d_out;

    // Workspace layout (float offsets; total ~147 MB, validated <= prior 172 MB)
    float* ws = (float*)d_ws;
    float* r_xnb  = ws;                        // 1,572,864 (xnb bf16); dead after gemm_xz
    float* r_inwT = r_xnb + 1572864;           // 2,359,296 (inwT bf16); dead after gemm_xz
    float* r_outwT= r_inwT + 2359296;          // 1,179,648 (outwT bf16); live till gemm_out
    float* r_xib  = r_outwT + 1179648;         // 6,291,456 (xi bf16); live through scan_p3
    float* r_szb  = r_xib + 6291456;           // 6,291,456 (sz bf16); live through scan_p3
    float* r_yvb  = r_szb + 6291456;           // 6,291,456 (Pbuf fp32 -> yvb bf16)
    float* hloc   = r_yvb + 6291456;           // 6,291,456
    float* hin    = hloc + 6291456;            // 6,291,456
    float* bcdt   = hin + 6291456;             // 270,336

    unsigned short* xnb   = (unsigned short*)r_xnb;
    unsigned short* inwT  = (unsigned short*)r_inwT;
    unsigned short* outwT = (unsigned short*)r_outwT;
    unsigned short* xib   = (unsigned short*)r_xib;
    unsigned short* szb   = (unsigned short*)r_szb;
    unsigned short* yvb   = (unsigned short*)r_yvb;  // written in p3 (Pbuf dead after p2)
    float* bcdt_part = r_xnb;                        // 1.62M fl; xnb/inwT dead after gemm_xz
    float* Pbuf = r_yvb;                             // 6.29M fl; consumed by p2 before p3 writes yvb

    // 1. LayerNorm -> bf16
    ln_kernel<<<NTOK, 256, 0, stream>>>(x, ln_g, ln_b, xnb);
    // 2. weight transpose-casts
    {
        dim3 g1(6144 / 32, DMODEL / 32);
        cast_inwT<<<g1, 256, 0, stream>>>(f_inw, b_inw, inwT);
        dim3 g2(DMODEL / 32, 3072 / 32);
        cast_outwT<<<g2, 256, 0, stream>>>(f_outw, b_outw, alpha, outwT);
    }
    // 3. xz GEMM (MFMA, async staging + swizzle + LDS-bounce epilogue)
    {
        dim3 grid(6144 / 128, NTOK / 128);
        gemm_xz_mfma<<<grid, 256, 0, stream>>>(xnb, inwT, xib, szb);
    }
    // 4. fused conv + bcdt split-K GEMM + reduce
    {
        dim3 g(2 * NTOK / 64, KSPLIT);
        bcdt_conv_gemm<<<g, 256, 0, stream>>>(xib, f_cw, f_cb, b_cw, b_cb,
                                              f_xw, b_xw, bcdt_part);
        bcdt_reduce<<<(2 * NTOK * NBCDT + 255) / 256, 256, 0, stream>>>(bcdt_part, bcdt);
    }
    // 5. chunked scan (thread-per-channel, TC=32 -> 1536 blocks/phase)
    {
        dim3 grid1(DINNER / 256, NCHUNK, 4);
        scan_p1<<<grid1, 256, 0, stream>>>(xib, bcdt, f_cw, f_cb, b_cw, b_cb,
                                           f_dtw, f_dtb, f_Alog,
                                           b_dtw, b_dtb, b_Alog, Pbuf, hloc);
        scan_p2<<<(4 * DINNER * NSTATE) / 256, 256, 0, stream>>>(Pbuf, hloc, hin);
        scan_p3<<<grid1, 256, 0, stream>>>(xib, bcdt, szb, hin,
                                           f_cw, f_cb, b_cw, b_cb,
                                           f_dtw, f_dtb, f_Alog, f_D,
                                           b_dtw, b_dtb, b_Alog, b_D, yvb);
    }
    // 6. out GEMM (MFMA, async staging + swizzle) + residual
    {
        dim3 grid(DMODEL / 64, NTOK / 128);
        gemm_out_mfma<<<grid, 256, 0, stream>>>(yvb, outwT, x, out);
    }
}

// Round 11
// 437.048 us; speedup vs baseline: 1.1824x; 1.0180x over previous
//
#include <hip/hip_runtime.h>
#include <cstddef>
#include <cstdint>

// Problem constants (fixed by reference)
#define DMODEL 768
#define DINNER 1536
#define NSTATE 16
#define LSEQ   2048
#define NB     2
#define NTOK   (NB*LSEQ)        // 4096 tokens
#define NBCDT  33               // 1 + 2*16

// Chunked scan parameters
#define TC     32               // timesteps per chunk (1536 blocks/phase)
#define NCHUNK (LSEQ/TC)        // 64
#define KSPLIT 6                // bcdt split-K factor (atomic accumulate)
#define LOG2E  1.44269504f

typedef __bf16 bf16x8 __attribute__((ext_vector_type(8)));
typedef float  floatx4 __attribute__((ext_vector_type(4)));
typedef unsigned short us8 __attribute__((ext_vector_type(8)));

__device__ __forceinline__ float exp2_hw(float x) { return __builtin_amdgcn_exp2f(x); }
__device__ __forceinline__ float silu_f(float x) { return x / (1.f + expf(-x)); }
__device__ __forceinline__ float clip1e4(float x) {
    return __builtin_amdgcn_fmed3f(x, -1e4f, 1e4f);
}
__device__ __forceinline__ unsigned short f2bf(float f) {   // RNE float->bf16 bits
    unsigned int u = __float_as_uint(f);
    unsigned int r = u + 0x7fffu + ((u >> 16) & 1u);
    return (unsigned short)(r >> 16);
}
__device__ __forceinline__ float bf2f(unsigned short u) {
    return __uint_as_float((unsigned int)u << 16);
}
__device__ __forceinline__ unsigned int pack2bf(float a, float b) {
    unsigned int ua = __float_as_uint(a); ua = ua + 0x7fffu + ((ua >> 16) & 1u);
    unsigned int ub = __float_as_uint(b); ub = ub + 0x7fffu + ((ub >> 16) & 1u);
    return (ua >> 16) | (ub & 0xffff0000u);
}
__device__ __forceinline__ void ld_lds16(unsigned short* lds, const unsigned short* g) {
    __builtin_amdgcn_global_load_lds(
        (const __attribute__((address_space(1))) unsigned int*)g,
        (__attribute__((address_space(3))) unsigned int*)lds,
        16, 0, 0);
}

// ---------------------------------------------------------------------------
// Kernel 1: LayerNorm -> bf16, plus bcdt zero-init (atomic target).
// ---------------------------------------------------------------------------
__global__ void ln_kernel(const float* __restrict__ x,
                          const float* __restrict__ g,
                          const float* __restrict__ be,
                          unsigned short* __restrict__ xnb,
                          float* __restrict__ bcdt) {
    int row = blockIdx.x;
    int tid = threadIdx.x;
    // zero the bcdt accumulator (270,336 floats; grid covers 1,048,576 slots)
    int zi = row * 256 + tid;
    if (zi < 2 * NTOK * NBCDT) bcdt[zi] = 0.f;
    const float* xr = x + (size_t)row * DMODEL;
    float s = 0.f, ss = 0.f;
    for (int i = tid; i < DMODEL; i += 256) {
        float v = xr[i];
        s += v; ss += v * v;
    }
    for (int o = 32; o >= 1; o >>= 1) {
        s  += __shfl_xor(s,  o, 64);
        ss += __shfl_xor(ss, o, 64);
    }
    __shared__ float sS[4], sSS[4];
    int w = tid >> 6;
    if ((tid & 63) == 0) { sS[w] = s; sSS[w] = ss; }
    __syncthreads();
    s  = sS[0] + sS[1] + sS[2] + sS[3];
    ss = sSS[0] + sSS[1] + sSS[2] + sSS[3];
    float mu = s / DMODEL;
    float var = ss / DMODEL - mu * mu;
    float rstd = rsqrtf(var + 1e-5f);
    unsigned short* xo = xnb + (size_t)row * DMODEL;
    for (int i = tid; i < DMODEL; i += 256)
        xo[i] = f2bf((xr[i] - mu) * rstd * g[i] + be[i]);
}

// ---------------------------------------------------------------------------
// Kernel 2: merged transpose-cast of in-proj and (blend-scaled) out-proj.
// blocks [0, 4608): inwT[n][k], n in [0,6144), k in [0,768)
// blocks [4608, 6912): outwT[n][k], n in [0,768), k in [0,3072)
// ---------------------------------------------------------------------------
__global__ __launch_bounds__(256)
void cast_weights(const float* __restrict__ f_inw, const float* __restrict__ b_inw,
                  const float* __restrict__ f_outw, const float* __restrict__ b_outw,
                  const float* __restrict__ alpha,
                  unsigned short* __restrict__ inwT, unsigned short* __restrict__ outwT) {
    __shared__ float t[32][33];
    int bid = blockIdx.x;
    int tid = threadIdx.x;
    int lr = tid >> 5, lc = tid & 31;
    if (bid < 4608) {
        int n0 = (bid % 192) * 32;
        int k0 = (bid / 192) * 32;
        const float* w = (n0 >= 3072) ? b_inw : f_inw;
        int nb = (n0 >= 3072) ? (n0 - 3072) : n0;
        #pragma unroll
        for (int r = 0; r < 4; r++)
            t[r * 8 + lr][lc] = w[(size_t)(k0 + r * 8 + lr) * 3072 + nb + lc];
        __syncthreads();
        #pragma unroll
        for (int r = 0; r < 4; r++)
            inwT[(size_t)(n0 + r * 8 + lr) * DMODEL + k0 + lc] = f2bf(t[lc][r * 8 + lr]);
    } else {
        bid -= 4608;
        float a = 1.f / (1.f + expf(-alpha[0]));
        int n0 = (bid % 24) * 32;
        int k0 = (bid / 24) * 32;
        const float* w = (k0 >= DINNER) ? b_outw : f_outw;
        float sc = (k0 >= DINNER) ? (1.f - a) : a;
        int kb = (k0 >= DINNER) ? (k0 - DINNER) : k0;
        #pragma unroll
        for (int r = 0; r < 4; r++)
            t[r * 8 + lr][lc] = w[(size_t)(kb + r * 8 + lr) * DMODEL + n0 + lc];
        __syncthreads();
        #pragma unroll
        for (int r = 0; r < 4; r++)
            outwT[(size_t)(n0 + r * 8 + lr) * 3072 + k0 + lc] = f2bf(sc * t[lc][r * 8 + lr]);
    }
}

// ---------------------------------------------------------------------------
// Kernel 3: xz GEMM via MFMA bf16, async LDS staging + XOR-swizzle + LDS-
// bounced coalesced epilogue.  M=4096, N=6144, K=768.  128x128, BK=64.
// ---------------------------------------------------------------------------
__global__ __launch_bounds__(256)
void gemm_xz_mfma(const unsigned short* __restrict__ xnb,
                  const unsigned short* __restrict__ inwT,
                  unsigned short* __restrict__ xi, unsigned short* __restrict__ sz) {
    __shared__ unsigned short SH[2 * 128 * 64];   // A | B staging; reused for C
    unsigned short* Asm = SH;
    unsigned short* Bsm = SH + 128 * 64;
    int tid = threadIdx.x;
    int bm = blockIdx.y * 128;
    int bn = blockIdx.x * 128;
    int wave = tid >> 6, lane = tid & 63;
    int wm = (wave & 1) * 64, wn = (wave >> 1) * 64;
    int col15 = lane & 15, quad = lane >> 4;
    int lrow = lane >> 3;                      // 0..7
    int lk   = (((lane & 7) ^ lrow) * 8);      // swizzled global chunk offset
    floatx4 acc[4][4];
    #pragma unroll
    for (int i = 0; i < 4; i++)
        #pragma unroll
        for (int j = 0; j < 4; j++)
            acc[i][j] = (floatx4){0.f, 0.f, 0.f, 0.f};

    int sw = col15 & 7;
    for (int k0 = 0; k0 < DMODEL; k0 += 64) {
        #pragma unroll
        for (int i = 0; i < 4; i++) {
            int r8 = wave * 32 + i * 8;
            int ra = r8 + lrow;
            ld_lds16(&Asm[r8 * 64], &xnb[(size_t)(bm + ra) * DMODEL + k0 + lk]);
            ld_lds16(&Bsm[r8 * 64], &inwT[(size_t)(bn + ra) * DMODEL + k0 + lk]);
        }
        __syncthreads();
        #pragma unroll
        for (int k2 = 0; k2 < 2; k2++) {
            bf16x8 af[4], bf_[4];
            int pc = ((k2 * 4 + quad) ^ sw) * 8;
            #pragma unroll
            for (int mt = 0; mt < 4; mt++)
                af[mt] = *(const bf16x8*)(&Asm[(wm + mt * 16 + col15) * 64 + pc]);
            #pragma unroll
            for (int nt = 0; nt < 4; nt++)
                bf_[nt] = *(const bf16x8*)(&Bsm[(wn + nt * 16 + col15) * 64 + pc]);
            #pragma unroll
            for (int mt = 0; mt < 4; mt++)
                #pragma unroll
                for (int nt = 0; nt < 4; nt++)
                    acc[mt][nt] = __builtin_amdgcn_mfma_f32_16x16x32_bf16(
                        af[mt], bf_[nt], acc[mt][nt], 0, 0, 0);
        }
        __syncthreads();
    }
    // ---- epilogue: LDS bounce, coalesced bf16 stores ----
    float* Cst = (float*)SH;                   // [128][36] fp32
    int half = wn >> 6;
    int erow = tid >> 1;
    int g0 = (tid & 1) * 2;
    #pragma unroll
    for (int nt = 0; nt < 4; nt++) {
        __syncthreads();
        #pragma unroll
        for (int mt = 0; mt < 4; mt++)
            #pragma unroll
            for (int r = 0; r < 4; r++)
                Cst[(wm + mt * 16 + quad * 4 + r) * 36 + half * 16 + col15] = acc[mt][nt][r];
        __syncthreads();
        #pragma unroll
        for (int gi = 0; gi < 2; gi++) {
            int g = g0 + gi;
            int hh = g >> 1, c8 = (g & 1) * 8;
            const float* src = &Cst[erow * 36 + hh * 16 + c8];
            float4 v0 = *(const float4*)(src);
            float4 v1 = *(const float4*)(src + 4);
            int gn = bn + hh * 64 + nt * 16 + c8;
            int dir = (gn >= 3072) ? 1 : 0;
            int cc = gn - dir * 3072;
            size_t base = ((size_t)dir * NTOK + (bm + erow)) * DINNER;
            if (cc < DINNER) {
                uint4 pk = { pack2bf(v0.x, v0.y), pack2bf(v0.z, v0.w),
                             pack2bf(v1.x, v1.y), pack2bf(v1.z, v1.w) };
                *(uint4*)(&xi[base + cc]) = pk;
            } else {
                v0.x = silu_f(v0.x); v0.y = silu_f(v0.y);
                v0.z = silu_f(v0.z); v0.w = silu_f(v0.w);
                v1.x = silu_f(v1.x); v1.y = silu_f(v1.y);
                v1.z = silu_f(v1.z); v1.w = silu_f(v1.w);
                uint4 pk = { pack2bf(v0.x, v0.y), pack2bf(v0.z, v0.w),
                             pack2bf(v1.x, v1.y), pack2bf(v1.z, v1.w) };
                *(uint4*)(&sz[base + cc - DINNER]) = pk;
            }
        }
    }
}

// ---------------------------------------------------------------------------
// Kernel 4: FUSED conv + bcdt split-K GEMM, atomic accumulate into bcdt.
// grid (128 row-blocks, KSPLIT).
// ---------------------------------------------------------------------------
__global__ __launch_bounds__(256)
void bcdt_conv_gemm(const unsigned short* __restrict__ xi,
                    const float* __restrict__ f_cw, const float* __restrict__ f_cb,
                    const float* __restrict__ b_cw, const float* __restrict__ b_cb,
                    const float* __restrict__ f_xw, const float* __restrict__ b_xw,
                    float* __restrict__ bcdt) {
    __shared__ unsigned short Xs[67 * 32];
    __shared__ float As[64][33];
    __shared__ float Ws[32 * 33];
    __shared__ float Wc[32][4];
    __shared__ float Cb[32];
    int r0 = blockIdx.x * 64;
    int kc = blockIdx.y;
    int dirb = r0 >> 11;
    int dir = dirb >> 1, b = dirb & 1;
    int t0 = r0 & 2047;
    const float* xw = dir ? b_xw : f_xw;
    const float* cw = dir ? b_cw : f_cw;
    const float* cb = dir ? b_cb : f_cb;
    int tid = threadIdx.x;
    int m = tid >> 2, jq = tid & 3;
    float acc[9] = {};
    size_t xibase = ((size_t)dir * NTOK + (size_t)b * LSEQ) * DINNER;
    int kend = kc * 256 + 256;
    for (int k0 = kc * 256; k0 < kend; k0 += 32) {
        if (tid < 32) {
            float4 w4 = *(const float4*)(cw + (size_t)(k0 + tid) * 4);
            Wc[tid][0] = w4.x; Wc[tid][1] = w4.y; Wc[tid][2] = w4.z; Wc[tid][3] = w4.w;
            Cb[tid] = cb[k0 + tid];
        }
        for (int j = tid; j < 67 * 16; j += 256) {
            int row = j >> 4, c2 = (j & 15) * 2;
            int u = t0 - 3 + row;
            unsigned int v = 0;
            if (u >= 0) {
                int l = dir ? (LSEQ - 1 - u) : u;
                v = *(const unsigned int*)(&xi[xibase + (size_t)l * DINNER + k0 + c2]);
            }
            *(unsigned int*)(&Xs[row * 32 + c2]) = v;
        }
        for (int i = tid; i < 32 * 33; i += 256)
            Ws[i] = xw[(size_t)k0 * 33 + i];
        __syncthreads();
        for (int j = tid; j < 64 * 32; j += 256) {
            int t = j >> 5, ch = j & 31;
            float a = Cb[ch];
            #pragma unroll
            for (int k = 0; k < 4; k++)
                a = fmaf(Wc[ch][k], bf2f(Xs[(t + k) * 32 + ch]), a);
            As[t][ch] = silu_f(a);
        }
        __syncthreads();
        #pragma unroll 8
        for (int k = 0; k < 32; k++) {
            float a = As[m][k];
            #pragma unroll
            for (int jj = 0; jj < 9; jj++) {
                int j = jq + jj * 4;
                if (j < 33) acc[jj] = fmaf(a, Ws[k * 33 + j], acc[jj]);
            }
        }
        __syncthreads();
    }
    #pragma unroll
    for (int jj = 0; jj < 9; jj++) {
        int j = jq + jj * 4;
        if (j < 33)
            atomicAdd(&bcdt[((size_t)r0 + m) * 33 + j], acc[jj]);
    }
}

// ---------------------------------------------------------------------------
// Kernel 5a: scan phase 1 -- thread per channel, h[16] in regs, inline conv.
// Stores hloc + Sdt (P recomputed in p2 from Sdt -- no Pbuf traffic).
// Clip dropped from inner loop: chunk decomposition already requires it
// inactive (verified: absmax passes).
// ---------------------------------------------------------------------------
__global__ __launch_bounds__(256)
void scan_p1(const unsigned short* __restrict__ xi, const float* __restrict__ bcdt,
             const float* __restrict__ f_cw, const float* __restrict__ f_cb,
             const float* __restrict__ b_cw, const float* __restrict__ b_cb,
             const float* __restrict__ f_dtw, const float* __restrict__ f_dtb,
             const float* __restrict__ f_Alog,
             const float* __restrict__ b_dtw, const float* __restrict__ b_dtb,
             const float* __restrict__ b_Alog,
             float* __restrict__ Sdtbuf, float* __restrict__ hloc) {
    int tid = threadIdx.x;
    int d = blockIdx.x * 256 + tid;
    int chunk = blockIdx.y;
    int dirb  = blockIdx.z;
    int dir = dirb >> 1, b = dirb & 1;
    const float* dtw  = dir ? b_dtw  : f_dtw;
    const float* dtb  = dir ? b_dtb  : f_dtb;
    const float* Alog = dir ? b_Alog : f_Alog;
    const float* cw   = dir ? b_cw   : f_cw;
    const float* cb   = dir ? b_cb   : f_cb;
    float dtw_d = dtw[d], dtb_d = dtb[d];
    float4 wc = *(const float4*)(cw + (size_t)d * 4);
    float cb_d = cb[d];
    float A2[NSTATE], h[NSTATE];
    #pragma unroll
    for (int s = 0; s < NSTATE; s++) {
        float al = fminf(fmaxf(Alog[d * NSTATE + s], -6.f), 6.f);
        A2[s] = -__expf(al) * LOG2E;
        h[s] = 0.f;
    }
    float Sdt = 0.f;
    int t0 = chunk * TC;
    size_t xbase = ((size_t)dir * NTOK + (size_t)b * LSEQ) * DINNER + d;
    long stride = dir ? -(long)DINNER : (long)DINNER;
    int l0 = dir ? (LSEQ - 1 - t0) : t0;
    const unsigned short* xp = xi + xbase + (size_t)l0 * DINNER;
    float xm3 = 0.f, xm2 = 0.f, xm1 = 0.f;
    if (chunk) {
        xm3 = bf2f(*(xp - 3 * stride));
        xm2 = bf2f(*(xp - 2 * stride));
        xm1 = bf2f(*(xp - 1 * stride));
    }
    size_t rbase = (size_t)dirb * LSEQ + (size_t)t0;
    const float* bc = bcdt + rbase * NBCDT;
    for (int t = 0; t < TC; t++) {
        float cur = bf2f(*xp); xp += stride;
        float xv = cb_d;
        xv = fmaf(wc.x, xm3, xv);
        xv = fmaf(wc.y, xm2, xv);
        xv = fmaf(wc.z, xm1, xv);
        xv = fmaf(wc.w, cur, xv);
        xv = silu_f(xv);
        xm3 = xm2; xm2 = xm1; xm1 = cur;
        float dt_raw = bc[t * NBCDT];
        float u = fmaf(dt_raw, dtw_d, dtb_d);
        float dt = fmaxf(u, 0.f) + __logf(1.f + __expf(-fabsf(u)));
        Sdt += dt;
        float dtx = dt * xv;
        #pragma unroll
        for (int s = 0; s < NSTATE; s++) {
            float Bv = bc[t * NBCDT + 1 + s];
            h[s] = fmaf(exp2_hw(dt * A2[s]), h[s], dtx * Bv);
        }
    }
    Sdtbuf[(size_t)chunk * (4 * DINNER) + (size_t)dirb * DINNER + d] = Sdt;
    size_t base = ((size_t)chunk * 4 + dirb) * ((size_t)DINNER * NSTATE) + (size_t)d * NSTATE;
    #pragma unroll
    for (int s = 0; s < NSTATE; s++)
        hloc[base + s] = h[s];
}

// ---------------------------------------------------------------------------
// Kernel 5b: phase 2 -- stitch chunk boundary states. P = exp2(A2 * Sdt).
// ---------------------------------------------------------------------------
__global__ void scan_p2(const float* __restrict__ Sdtbuf, const float* __restrict__ hloc,
                        const float* __restrict__ f_Alog, const float* __restrict__ b_Alog,
                        float* __restrict__ hin) {
    int i = blockIdx.x * 256 + threadIdx.x;   // [0, 4*DINNER*NSTATE)
    const int DS = DINNER * NSTATE;
    int dirb = i / DS;
    int rem = i - dirb * DS;
    int d = rem >> 4, s = rem & 15;
    const float* Alog = (dirb >> 1) ? b_Alog : f_Alog;
    float al = fminf(fmaxf(Alog[d * NSTATE + s], -6.f), 6.f);
    float A2 = -__expf(al) * LOG2E;
    float h = 0.f;
    const int stride = 4 * DS;                // 98304
    const int sstr = 4 * DINNER;              // 6144
    for (int c = 0; c < NCHUNK; c++) {
        size_t idx = (size_t)c * stride + i;
        hin[idx] = h;
        float P = exp2_hw(A2 * Sdtbuf[(size_t)c * sstr + dirb * DINNER + d]);
        h = clip1e4(fmaf(P, h, hloc[idx]));
    }
}

// ---------------------------------------------------------------------------
// Kernel 5c: phase 3 -- re-run from stitched h_in, inline conv, write bf16
// yvb [4096][3072].
// ---------------------------------------------------------------------------
__global__ __launch_bounds__(256)
void scan_p3(const unsigned short* __restrict__ xi, const float* __restrict__ bcdt,
             const unsigned short* __restrict__ sz, const float* __restrict__ hin,
             const float* __restrict__ f_cw, const float* __restrict__ f_cb,
             const float* __restrict__ b_cw, const float* __restrict__ b_cb,
             const float* __restrict__ f_dtw, const float* __restrict__ f_dtb,
             const float* __restrict__ f_Alog, const float* __restrict__ f_D,
             const float* __restrict__ b_dtw, const float* __restrict__ b_dtb,
             const float* __restrict__ b_Alog, const float* __restrict__ b_D,
             unsigned short* __restrict__ yvb) {
    int tid = threadIdx.x;
    int d = blockIdx.x * 256 + tid;
    int chunk = blockIdx.y;
    int dirb  = blockIdx.z;
    int dir = dirb >> 1, b = dirb & 1;
    const float* dtw  = dir ? b_dtw  : f_dtw;
    const float* dtb  = dir ? b_dtb  : f_dtb;
    const float* Alog = dir ? b_Alog : f_Alog;
    const float* Dp   = dir ? b_D    : f_D;
    const float* cw   = dir ? b_cw   : f_cw;
    const float* cb   = dir ? b_cb   : f_cb;
    float dtw_d = dtw[d], dtb_d = dtb[d], D_d = Dp[d];
    float4 wc = *(const float4*)(cw + (size_t)d * 4);
    float cb_d = cb[d];
    float A2[NSTATE], h[NSTATE];
    size_t hbase = ((size_t)chunk * 4 + dirb) * ((size_t)DINNER * NSTATE) + (size_t)d * NSTATE;
    #pragma unroll
    for (int s = 0; s < NSTATE; s++) {
        float al = fminf(fmaxf(Alog[d * NSTATE + s], -6.f), 6.f);
        A2[s] = -__expf(al) * LOG2E;
        h[s] = hin[hbase + s];
    }
    int t0 = chunk * TC;
    size_t xbase = ((size_t)dir * NTOK + (size_t)b * LSEQ) * DINNER + d;
    long stride = dir ? -(long)DINNER : (long)DINNER;
    int l0 = dir ? (LSEQ - 1 - t0) : t0;
    const unsigned short* xp = xi + xbase + (size_t)l0 * DINNER;
    const unsigned short* szp = sz + xbase + (size_t)l0 * DINNER;
    unsigned short* yp = yvb + ((size_t)(b * LSEQ + l0)) * 3072 + dir * DINNER + d;
    long ystride = stride * 2;                 // yvb row stride is 3072
    float xm3 = 0.f, xm2 = 0.f, xm1 = 0.f;
    if (chunk) {
        xm3 = bf2f(*(xp - 3 * stride));
        xm2 = bf2f(*(xp - 2 * stride));
        xm1 = bf2f(*(xp - 1 * stride));
    }
    size_t rbase = (size_t)dirb * LSEQ + (size_t)t0;
    const float* bc = bcdt + rbase * NBCDT;
    for (int t = 0; t < TC; t++) {
        float cur = bf2f(*xp); xp += stride;
        float xv = cb_d;
        xv = fmaf(wc.x, xm3, xv);
        xv = fmaf(wc.y, xm2, xv);
        xv = fmaf(wc.z, xm1, xv);
        xv = fmaf(wc.w, cur, xv);
        xv = silu_f(xv);
        xm3 = xm2; xm2 = xm1; xm1 = cur;
        float dt_raw = bc[t * NBCDT];
        float u = fmaf(dt_raw, dtw_d, dtb_d);
        float dt = fmaxf(u, 0.f) + __logf(1.f + __expf(-fabsf(u)));
        float dtx = dt * xv;
        float p = 0.f;
        #pragma unroll
        for (int s = 0; s < NSTATE; s++) {
            float Bv = bc[t * NBCDT + 1 + s];
            float Cv = bc[t * NBCDT + 1 + NSTATE + s];
            h[s] = fmaf(exp2_hw(dt * A2[s]), h[s], dtx * Bv);
            p = fmaf(h[s], Cv, p);
        }
        float szv = bf2f(*szp); szp += stride;
        float y = (p + xv * D_d) * szv;
        *yp = f2bf(y); yp += ystride;
    }
}

// ---------------------------------------------------------------------------
// Kernel 6: output GEMM via MFMA bf16 + residual, async staging + swizzle.
// M=4096, N=768, K=3072.  128x64 tile, BK=64.
// ---------------------------------------------------------------------------
__global__ __launch_bounds__(256)
void gemm_out_mfma(const unsigned short* __restrict__ yvb,
                   const unsigned short* __restrict__ outwT,
                   const float* __restrict__ x,
                   float* __restrict__ out) {
    __shared__ unsigned short Asm[128 * 64];
    __shared__ unsigned short Bsm[64 * 64];
    int tid = threadIdx.x;
    int bm = blockIdx.y * 128;
    int bn = blockIdx.x * 64;
    int wave = tid >> 6, lane = tid & 63;
    int wm = (wave & 1) * 64, wn = (wave >> 1) * 32;
    int col15 = lane & 15, quad = lane >> 4;
    int lrow = lane >> 3;
    int lk   = (((lane & 7) ^ lrow) * 8);
    floatx4 acc[4][2];
    #pragma unroll
    for (int i = 0; i < 4; i++)
        #pragma unroll
        for (int j = 0; j < 2; j++)
            acc[i][j] = (floatx4){0.f, 0.f, 0.f, 0.f};

    int sw = col15 & 7;
    for (int k0 = 0; k0 < 2 * DINNER; k0 += 64) {
        #pragma unroll
        for (int i = 0; i < 4; i++) {
            int r8 = wave * 32 + i * 8;
            ld_lds16(&Asm[r8 * 64], &yvb[(size_t)(bm + r8 + lrow) * 3072 + k0 + lk]);
        }
        #pragma unroll
        for (int i = 0; i < 2; i++) {
            int r8 = wave * 16 + i * 8;
            ld_lds16(&Bsm[r8 * 64], &outwT[(size_t)(bn + r8 + lrow) * 3072 + k0 + lk]);
        }
        __syncthreads();
        #pragma unroll
        for (int k2 = 0; k2 < 2; k2++) {
            bf16x8 af[4], bf_[2];
            int pc = ((k2 * 4 + quad) ^ sw) * 8;
            #pragma unroll
            for (int mt = 0; mt < 4; mt++)
                af[mt] = *(const bf16x8*)(&Asm[(wm + mt * 16 + col15) * 64 + pc]);
            #pragma unroll
            for (int nt = 0; nt < 2; nt++)
                bf_[nt] = *(const bf16x8*)(&Bsm[(wn + nt * 16 + col15) * 64 + pc]);
            #pragma unroll
            for (int mt = 0; mt < 4; mt++)
                #pragma unroll
                for (int nt = 0; nt < 2; nt++)
                    acc[mt][nt] = __builtin_amdgcn_mfma_f32_16x16x32_bf16(
                        af[mt], bf_[nt], acc[mt][nt], 0, 0, 0);
        }
        __syncthreads();
    }
    #pragma unroll
    for (int mt = 0; mt < 4; mt++) {
        #pragma unroll
        for (int nt = 0; nt < 2; nt++) {
            #pragma unroll
            for (int r = 0; r < 4; r++) {
                int row = bm + wm + mt * 16 + quad * 4 + r;
                int gn  = bn + wn + nt * 16 + col15;
                out[(size_t)row * DMODEL + gn] = acc[mt][nt][r] + x[(size_t)row * DMODEL + gn];
            }
        }
    }
}

// ---------------------------------------------------------------------------
extern "C" void kernel_launch(void* const* d_in, const int* in_sizes, int n_in,
                              void* d_out, int out_size, void* d_ws, size_t ws_size,
                              hipStream_t stream) {
    const float* x     = (const float*)d_in[0];
    const float* ln_g  = (const float*)d_in[1];
    const float* ln_b  = (const float*)d_in[2];
    const float* alpha = (const float*)d_in[3];
    const float* f_inw  = (const float*)d_in[4];
    const float* f_cw   = (const float*)d_in[5];
    const float* f_cb   = (const float*)d_in[6];
    const float* f_xw   = (const float*)d_in[7];
    const float* f_dtw  = (const float*)d_in[8];
    const float* f_dtb  = (const float*)d_in[9];
    const float* f_Alog = (const float*)d_in[10];
    const float* f_D    = (const float*)d_in[11];
    const float* f_outw = (const float*)d_in[12];
    const float* b_inw  = (const float*)d_in[13];
    const float* b_cw   = (const float*)d_in[14];
    const float* b_cb   = (const float*)d_in[15];
    const float* b_xw   = (const float*)d_in[16];
    const float* b_dtw  = (const float*)d_in[17];
    const float* b_dtb  = (const float*)d_in[18];
    const float* b_Alog = (const float*)d_in[19];
    const float* b_D    = (const float*)d_in[20];
    const float* b_outw = (const float*)d_in[21];
    float* out = (float*)d_out;

    // Workspace layout (float offsets; total 37.2M floats = 149 MB):
    float* ws = (float*)d_ws;
    float* r_xnb  = ws;                        // 1,572,864 (xnb bf16); dead after gemm_xz
    float* r_inwT = r_xnb + 1572864;           // 2,359,296 (inwT bf16); dead after gemm_xz
    float* r_outwT= r_inwT + 2359296;          // 1,179,648 (outwT bf16); live till gemm_out
    float* r_xib  = r_outwT + 1179648;         // 6,291,456 (xi bf16); live through scan_p3
    float* r_szb  = r_xib + 6291456;           // 6,291,456 (sz bf16); live through scan_p3
    float* r_yvb  = r_szb + 6291456;           // 6,291,456 (yvb bf16)
    float* hloc   = r_yvb + 6291456;           // 6,291,456
    float* hin    = hloc + 6291456;            // 6,291,456
    float* Sdtbuf = hin + 6291456;             // 393,216 (NCHUNK*4*DINNER)
    float* bcdt   = Sdtbuf + 393216;           // 270,336 (atomic accumulator)

    unsigned short* xnb   = (unsigned short*)r_xnb;
    unsigned short* inwT  = (unsigned short*)r_inwT;
    unsigned short* outwT = (unsigned short*)r_outwT;
    unsigned short* xib   = (unsigned short*)r_xib;
    unsigned short* szb   = (unsigned short*)r_szb;
    unsigned short* yvb   = (unsigned short*)r_yvb;

    // 1. LayerNorm -> bf16 (+ bcdt zero-init)
    ln_kernel<<<NTOK, 256, 0, stream>>>(x, ln_g, ln_b, xnb, bcdt);
    // 2. merged weight transpose-casts
    cast_weights<<<4608 + 2304, 256, 0, stream>>>(f_inw, b_inw, f_outw, b_outw,
                                                  alpha, inwT, outwT);
    // 3. xz GEMM (MFMA, async staging + swizzle + LDS-bounce epilogue)
    {
        dim3 grid(6144 / 128, NTOK / 128);
        gemm_xz_mfma<<<grid, 256, 0, stream>>>(xnb, inwT, xib, szb);
    }
    // 4. fused conv + bcdt split-K GEMM (atomic accumulate)
    {
        dim3 g(2 * NTOK / 64, KSPLIT);
        bcdt_conv_gemm<<<g, 256, 0, stream>>>(xib, f_cw, f_cb, b_cw, b_cb,
                                              f_xw, b_xw, bcdt);
    }
    // 5. chunked scan (thread-per-channel, TC=32 -> 1536 blocks/phase)
    {
        dim3 grid1(DINNER / 256, NCHUNK, 4);
        scan_p1<<<grid1, 256, 0, stream>>>(xib, bcdt, f_cw, f_cb, b_cw, b_cb,
                                           f_dtw, f_dtb, f_Alog,
                                           b_dtw, b_dtb, b_Alog, Sdtbuf, hloc);
        scan_p2<<<(4 * DINNER * NSTATE) / 256, 256, 0, stream>>>(Sdtbuf, hloc,
                                                                 f_Alog, b_Alog, hin);
        scan_p3<<<grid1, 256, 0, stream>>>(xib, bcdt, szb, hin,
                                           f_cw, f_cb, b_cw, b_cb,
                                           f_dtw, f_dtb, f_Alog, f_D,
                                           b_dtw, b_dtb, b_Alog, b_D, yvb);
    }
    // 6. out GEMM (MFMA, async staging + swizzle) + residual
    {
        dim3 grid(DMODEL / 64, NTOK / 128);
        gemm_out_mfma<<<grid, 256, 0, stream>>>(yvb, outwT, x, out);
    }
}